// Round 1
// baseline (753.928 us; speedup 1.0000x reference)
//
#include <hip/hip_runtime.h>
#include <hip/hip_bf16.h>
#include <cstdint>

#define C_DIM 128
#define E_DIM 64
#define B_DIM 8192

// ---------- bf16 helpers (manual RNE pack/unpack, keeps everything explicit) ----------
__device__ __forceinline__ uint32_t f2bf(float a) {
    uint32_t u = __float_as_uint(a);
    return (u + 0x7fffu + ((u >> 16) & 1u)) >> 16;   // round-to-nearest-even
}
__device__ __forceinline__ float bf2f_lo(uint32_t u) { return __uint_as_float(u << 16); }
__device__ __forceinline__ float bf2f_hi(uint32_t u) { return __uint_as_float(u & 0xffff0000u); }

// ---------- K0: wT[n][c] = (softmax(q, axis=1) * (1-I))[c][n]  ----------
__global__ __launch_bounds__(128) void k0_softmax_T(const float* __restrict__ q,
                                                    float* __restrict__ wT) {
    const int c = blockIdx.x;
    const int t = threadIdx.x;           // n
    __shared__ float redM[2], redS[2];
    float v = q[c * C_DIM + t];
    float m = v;
    #pragma unroll
    for (int o = 32; o > 0; o >>= 1) m = fmaxf(m, __shfl_xor(m, o));
    if ((t & 63) == 0) redM[t >> 6] = m;
    __syncthreads();
    m = fmaxf(redM[0], redM[1]);
    float e = expf(v - m);
    float s = e;
    #pragma unroll
    for (int o = 32; o > 0; o >>= 1) s += __shfl_xor(s, o);
    if ((t & 63) == 0) redS[t >> 6] = s;
    __syncthreads();
    s = redS[0] + redS[1];
    float w = e / s;
    if (t == c) w = 0.f;                 // zero diagonal AFTER softmax (matches reference)
    wT[t * C_DIM + c] = w;               // transposed for uniform scalar loads in k2
}

// ---------- K1: v[r][c][e] (L2-normalized), stored as packed bf16x2 ----------
__global__ __launch_bounds__(256) void k1_value(const float* __restrict__ samples,
                                                const float* __restrict__ W1,
                                                const float* __restrict__ b1,
                                                const float* __restrict__ W2,
                                                const float* __restrict__ b2,
                                                uint32_t* __restrict__ vout,
                                                int rowOff) {
    __shared__ float sW2[E_DIM * E_DIM];
    __shared__ float sW1[E_DIM], sB1[E_DIM], sB2[E_DIM];
    const int c = blockIdx.x;
    const int t = threadIdx.x;
    for (int i = t; i < E_DIM * E_DIM; i += 256) sW2[i] = W2[c * E_DIM * E_DIM + i];
    if (t < E_DIM) { sW1[t] = W1[c * E_DIM + t]; sB1[t] = b1[c * E_DIM + t]; sB2[t] = b2[c * E_DIM + t]; }
    __syncthreads();

    const int r = blockIdx.y * 256 + t;  // chunk-local row
    const float s = samples[(size_t)(rowOff + r) * C_DIM + c];

    float h[E_DIM];
    #pragma unroll
    for (int e = 0; e < E_DIM; ++e) h[e] = fmaxf(fmaf(s, sW1[e], sB1[e]), 0.f);

    float v[E_DIM];
    float ss = 0.f;
    #pragma unroll
    for (int f = 0; f < E_DIM; ++f) {
        float acc = sB2[f];
        #pragma unroll
        for (int e = 0; e < E_DIM; ++e) acc = fmaf(h[e], sW2[f * E_DIM + e], acc);
        v[f] = acc;
        ss = fmaf(acc, acc, ss);
    }
    const float sc = 1.0f / fmaxf(sqrtf(ss), 1e-12f);

    uint32_t* dst = vout + ((size_t)r * C_DIM + c) * (E_DIM / 2);
    #pragma unroll
    for (int f = 0; f < E_DIM; f += 2)
        dst[f >> 1] = f2bf(v[f] * sc) | (f2bf(v[f + 1] * sc) << 16);
}

// ---------- K2: ctx[r][c][e] = sum_n wT[n][c] * v[r][n][e], in place over v ----------
__global__ __launch_bounds__(256) void k2_ctx(const float* __restrict__ wT,
                                              uint32_t* __restrict__ v) {
    __shared__ uint32_t sv[4 * C_DIM * (E_DIM / 2)];   // 4 rows x 128 n x 32 dwords = 64 KB
    const int t = threadIdx.x;
    const size_t r0 = (size_t)blockIdx.x * 4;

    // stage 4 batch rows (all n, all e) into LDS, coalesced uint4
    const uint4* gsrc = (const uint4*)(v + r0 * C_DIM * (E_DIM / 2));
    uint4* ldst = (uint4*)sv;
    #pragma unroll
    for (int i = 0; i < 16; ++i) ldst[t + 256 * i] = gsrc[t + 256 * i];
    __syncthreads();

    const int b = t >> 6;                // wave per row
    const int e = t & 63;                // lane = embedding index
    const uint32_t* svrow = sv + b * C_DIM * (E_DIM / 2) + (e >> 1);
    const int hi = e & 1;
    uint16_t* outp = (uint16_t*)v;

    #pragma unroll 1
    for (int cg = 0; cg < 4; ++cg) {     // 32 output columns at a time
        float acc[32];
        #pragma unroll
        for (int j = 0; j < 32; ++j) acc[j] = 0.f;
        for (int n = 0; n < C_DIM; ++n) {
            const uint32_t pr = svrow[(size_t)n * (E_DIM / 2)];
            const float vv = __uint_as_float(hi ? (pr & 0xffff0000u) : (pr << 16));
            const float* wrow = wT + n * C_DIM + cg * 32;   // uniform -> s_load
            #pragma unroll
            for (int j = 0; j < 32; ++j) acc[j] = fmaf(wrow[j], vv, acc[j]);
        }
        #pragma unroll
        for (int j = 0; j < 32; ++j) {
            const int cc = cg * 32 + j;
            outp[(((r0 + b) * C_DIM) + cc) * E_DIM + e] = (uint16_t)f2bf(acc[j]);
        }
    }
}

// ---------- K3: out[r][c] = P2[c] . relu(P1[c] @ ctx[r][c][:] + pb1[c]) + pb2[c] ----------
__global__ __launch_bounds__(256) void k3_out(const uint32_t* __restrict__ ctx,
                                              const float* __restrict__ P1,
                                              const float* __restrict__ pb1,
                                              const float* __restrict__ P2,
                                              const float* __restrict__ pb2,
                                              float* __restrict__ out,
                                              int rowOff) {
    __shared__ float sP1[E_DIM * E_DIM];
    __shared__ float sPb1[E_DIM], sP2[E_DIM];
    const int c = blockIdx.x;
    const int t = threadIdx.x;
    for (int i = t; i < E_DIM * E_DIM; i += 256) sP1[i] = P1[c * E_DIM * E_DIM + i];
    if (t < E_DIM) { sPb1[t] = pb1[c * E_DIM + t]; sP2[t] = P2[c * E_DIM + t]; }
    __syncthreads();

    const int r = blockIdx.y * 256 + t;  // chunk-local row
    const uint4* src = (const uint4*)(ctx + ((size_t)r * C_DIM + c) * (E_DIM / 2));
    float cx[E_DIM];
    #pragma unroll
    for (int i = 0; i < 8; ++i) {
        const uint4 pk = src[i];
        cx[i * 8 + 0] = bf2f_lo(pk.x); cx[i * 8 + 1] = bf2f_hi(pk.x);
        cx[i * 8 + 2] = bf2f_lo(pk.y); cx[i * 8 + 3] = bf2f_hi(pk.y);
        cx[i * 8 + 4] = bf2f_lo(pk.z); cx[i * 8 + 5] = bf2f_hi(pk.z);
        cx[i * 8 + 6] = bf2f_lo(pk.w); cx[i * 8 + 7] = bf2f_hi(pk.w);
    }

    float o = pb2[c];
    #pragma unroll 4
    for (int f = 0; f < E_DIM; ++f) {
        float acc = sPb1[f];
        #pragma unroll
        for (int e = 0; e < E_DIM; ++e) acc = fmaf(cx[e], sP1[f * E_DIM + e], acc);
        o = fmaf(fmaxf(acc, 0.f), sP2[f], o);
    }
    out[(size_t)(rowOff + r) * C_DIM + c] = o;
}

// ---------- host launch ----------
extern "C" void kernel_launch(void* const* d_in, const int* in_sizes, int n_in,
                              void* d_out, int out_size, void* d_ws, size_t ws_size,
                              hipStream_t stream) {
    const float* samples = (const float*)d_in[0];
    const float* W1  = (const float*)d_in[1];
    const float* b1  = (const float*)d_in[2];
    const float* W2  = (const float*)d_in[3];
    const float* b2  = (const float*)d_in[4];
    const float* q   = (const float*)d_in[5];
    const float* P1  = (const float*)d_in[6];
    const float* pb1 = (const float*)d_in[7];
    const float* P2  = (const float*)d_in[8];
    const float* pb2 = (const float*)d_in[9];
    float* out = (float*)d_out;

    float* wT = (float*)d_ws;                                   // 64 KB
    uint32_t* vbuf = (uint32_t*)((char*)d_ws + 65536);          // bf16 v/ctx staging

    // batch chunking sized to workspace (16 KB of bf16 per batch row)
    size_t avail = (ws_size > 65536) ? ws_size - 65536 : 0;
    long maxRows = (long)(avail / ((size_t)C_DIM * E_DIM * 2));
    maxRows = (maxRows / 256) * 256;
    if (maxRows > B_DIM) maxRows = B_DIM;
    if (maxRows < 256) maxRows = 256;

    k0_softmax_T<<<dim3(C_DIM), dim3(C_DIM), 0, stream>>>(q, wT);
    for (int off = 0; off < B_DIM; off += (int)maxRows) {
        const int rows = (int)(((long)(B_DIM - off) < maxRows) ? (B_DIM - off) : maxRows);
        k1_value<<<dim3(C_DIM, rows / 256), 256, 0, stream>>>(samples, W1, b1, W2, b2, vbuf, off);
        k2_ctx<<<dim3(rows / 4), 256, 0, stream>>>(wT, vbuf);
        k3_out<<<dim3(C_DIM, rows / 256), 256, 0, stream>>>(vbuf, P1, pb1, P2, pb2, out, off);
    }
}

// Round 2
// 351.373 us; speedup vs baseline: 2.1457x; 2.1457x over previous
//
#include <hip/hip_runtime.h>
#include <hip/hip_bf16.h>
#include <cstdint>

#define C_DIM 128
#define E_DIM 64
#define B_DIM 8192

typedef __attribute__((ext_vector_type(8))) short short8;
typedef __attribute__((ext_vector_type(4))) float f32x4;

union Frag8 { short8 v; short s[8]; uint32_t u[4]; };

__device__ __forceinline__ unsigned short bfbits(float x) {
    union { __hip_bfloat16 h; unsigned short u; } cv;
    cv.h = __float2bfloat16(x);
    return cv.u;
}
__device__ __forceinline__ float bits2f(unsigned short b) {
    return __uint_as_float(((uint32_t)b) << 16);
}

// ---------- K0: w = softmax(q,axis=1), zero diag, split hi/lo bf16, layout [c][n] ----------
__global__ __launch_bounds__(128) void k0_softmax(const float* __restrict__ q,
                                                  unsigned short* __restrict__ whi,
                                                  unsigned short* __restrict__ wlo) {
    const int c = blockIdx.x;
    const int t = threadIdx.x;            // n
    __shared__ float redM[2], redS[2];
    float v = q[c * C_DIM + t];
    float m = v;
    #pragma unroll
    for (int o = 32; o > 0; o >>= 1) m = fmaxf(m, __shfl_xor(m, o));
    if ((t & 63) == 0) redM[t >> 6] = m;
    __syncthreads();
    m = fmaxf(redM[0], redM[1]);
    float e = expf(v - m);
    float s = e;
    #pragma unroll
    for (int o = 32; o > 0; o >>= 1) s += __shfl_xor(s, o);
    if ((t & 63) == 0) redS[t >> 6] = s;
    __syncthreads();
    s = redS[0] + redS[1];
    float w = e / s;
    if (t == c) w = 0.f;                  // zero diagonal AFTER softmax
    unsigned short hb = bfbits(w);
    whi[c * C_DIM + t] = hb;
    wlo[c * C_DIM + t] = bfbits(w - bits2f(hb));
}

// ---------- KP: elementwise hi/lo bf16 split of a f32 weight tensor ----------
__global__ __launch_bounds__(256) void kP_split(const float* __restrict__ src,
                                                unsigned short* __restrict__ hi,
                                                unsigned short* __restrict__ lo) {
    const int i = blockIdx.x * 256 + threadIdx.x;   // index in float4 units
    const float4 v = ((const float4*)src)[i];
    float f[4] = {v.x, v.y, v.z, v.w};
    unsigned short h[4], l[4];
    #pragma unroll
    for (int j = 0; j < 4; ++j) {
        h[j] = bfbits(f[j]);
        l[j] = bfbits(f[j] - bits2f(h[j]));
    }
    ((ushort4*)hi)[i] = make_ushort4(h[0], h[1], h[2], h[3]);
    ((ushort4*)lo)[i] = make_ushort4(l[0], l[1], l[2], l[3]);
}

// ---------- K1: value MLP + L2 norm, MFMA. Output V[r][n8][e][8n] bf16 ----------
// block = 64 rows x 8 columns, 8 waves (1 column each). D: m=r, n=f.
__global__ __launch_bounds__(512) void k1_value(
        const float* __restrict__ samples, const float* __restrict__ W1,
        const float* __restrict__ b1, const unsigned short* __restrict__ W2hi,
        const unsigned short* __restrict__ W2lo, const float* __restrict__ b2,
        uint32_t* __restrict__ vbuf, int rowOff) {
    __shared__ unsigned short sOut[64 * 64 * 8];   // [r][f][c_local], 64KB, XOR-swizzled
    const int t = threadIdx.x;
    const int rt = blockIdx.x, cg = blockIdx.y;
    const int r0 = rt * 64;
    const int cl = t >> 6;                 // wave = local column
    const int lane = t & 63;
    const int lm = lane & 15, lg = lane >> 4;
    const int c = cg * 8 + cl;

    // per-lane scalars: samples for the 4 M-tiles this lane's A-rows need
    float sv[4];
    #pragma unroll
    for (int mt = 0; mt < 4; ++mt)
        sv[mt] = samples[(size_t)(rowOff + r0 + mt * 16 + lm) * C_DIM + c];

    // per-lane W1/b1 slices (k-contiguous 8 elems per k-step)
    float w1r[2][8], b1r[2][8];
    #pragma unroll
    for (int ks = 0; ks < 2; ++ks) {
        const float* wp = W1 + (size_t)c * 64 + ks * 32 + lg * 8;
        const float* bp = b1 + (size_t)c * 64 + ks * 32 + lg * 8;
        #pragma unroll
        for (int j = 0; j < 8; ++j) { w1r[ks][j] = wp[j]; b1r[ks][j] = bp[j]; }
    }
    float b2r[4];
    #pragma unroll
    for (int nt = 0; nt < 4; ++nt) b2r[nt] = b2[(size_t)c * 64 + nt * 16 + lm];

    f32x4 acc[4][4];
    #pragma unroll
    for (int mt = 0; mt < 4; ++mt)
        #pragma unroll
        for (int nt = 0; nt < 4; ++nt)
            acc[mt][nt] = (f32x4){0.f, 0.f, 0.f, 0.f};

    #pragma unroll
    for (int ks = 0; ks < 2; ++ks) {
        short8 afr[4];
        #pragma unroll
        for (int mt = 0; mt < 4; ++mt) {
            Frag8 af;
            #pragma unroll
            for (int j = 0; j < 8; ++j)
                af.s[j] = (short)bfbits(fmaxf(fmaf(sv[mt], w1r[ks][j], b1r[ks][j]), 0.f));
            afr[mt] = af.v;
        }
        #pragma unroll
        for (int nt = 0; nt < 4; ++nt) {
            const size_t wb = ((size_t)c * 64 + nt * 16 + lm) * 64 + ks * 32 + lg * 8;
            const short8 bh = *(const short8*)(W2hi + wb);
            const short8 bl = *(const short8*)(W2lo + wb);
            #pragma unroll
            for (int mt = 0; mt < 4; ++mt) {
                acc[mt][nt] = __builtin_amdgcn_mfma_f32_16x16x32_bf16(afr[mt], bh, acc[mt][nt], 0, 0, 0);
                acc[mt][nt] = __builtin_amdgcn_mfma_f32_16x16x32_bf16(afr[mt], bl, acc[mt][nt], 0, 0, 0);
            }
        }
    }

    // add b2, sum of squares over f (lane-local over nt, butterfly over lm lanes)
    float rsc[4][4];
    #pragma unroll
    for (int mt = 0; mt < 4; ++mt)
        #pragma unroll
        for (int i = 0; i < 4; ++i) {
            float s2 = 0.f;
            #pragma unroll
            for (int nt = 0; nt < 4; ++nt) {
                float vv = acc[mt][nt][i] + b2r[nt];
                acc[mt][nt][i] = vv;
                s2 = fmaf(vv, vv, s2);
            }
            s2 += __shfl_xor(s2, 1); s2 += __shfl_xor(s2, 2);
            s2 += __shfl_xor(s2, 4); s2 += __shfl_xor(s2, 8);
            rsc[mt][i] = 1.f / fmaxf(sqrtf(s2), 1e-12f);
        }

    // repack into LDS [r][f][c_local] bf16, XOR-swizzled by row
    #pragma unroll
    for (int mt = 0; mt < 4; ++mt)
        #pragma unroll
        for (int i = 0; i < 4; ++i) {
            const int r = mt * 16 + lg * 4 + i;
            const uint32_t rowbase = (uint32_t)r * 1024u;
            const uint32_t swz = (uint32_t)(r & 7) << 4;
            #pragma unroll
            for (int nt = 0; nt < 4; ++nt) {
                const int f = nt * 16 + lm;
                const uint32_t bo = (rowbase + (uint32_t)f * 16u + (uint32_t)cl * 2u) ^ swz;
                *(unsigned short*)((char*)sOut + bo) = bfbits(acc[mt][nt][i] * rsc[mt][i]);
            }
        }
    __syncthreads();

    // coalesced writeout: V[r][n8=cg][f][8n] -> per (r): 1KB contiguous
    #pragma unroll
    for (int it = 0; it < 8; ++it) {
        const int chunk = t + it * 512;
        const int r = chunk >> 6, f = chunk & 63;
        const uint32_t lb = ((uint32_t)r * 1024u + (uint32_t)f * 16u) ^ ((uint32_t)(r & 7) << 4);
        const uint4 val = *(const uint4*)((const char*)sOut + lb);
        ((uint4*)vbuf)[((size_t)(r0 + r) * 16 + cg) * 64 + f] = val;
    }
}

// ---------- K2: ctx[r][c][e] = sum_n w[c,n] V[r,n,e], MFMA, in-place over V ----------
// block = 2 rows, 4 waves: wave = (row, c-half). M=e, N=c, K=n.
__global__ __launch_bounds__(256) void k2_ctx(
        const unsigned short* __restrict__ whi, const unsigned short* __restrict__ wlo,
        uint32_t* __restrict__ buf) {
    __shared__ uint4 sV4[2048];            // 32KB = two consecutive V rows (linear)
    const int t = threadIdx.x;
    const int lane = t & 63, wv = t >> 6;
    const int lm = lane & 15, lg = lane >> 4;
    const size_t gr0 = (size_t)blockIdx.x * 2;

    const uint4* gsrc = (const uint4*)((const char*)buf + gr0 * 16384);
    #pragma unroll
    for (int i = 0; i < 8; ++i) sV4[t + i * 256] = gsrc[t + i * 256];
    __syncthreads();

    const int rl = wv >> 1, ch = wv & 1;
    const size_t gr = gr0 + rl;
    const char* sRow = (const char*)sV4 + rl * 16384;
    const int c0 = ch * 64;

    f32x4 acc[4][4];                       // [et][nt]
    #pragma unroll
    for (int et = 0; et < 4; ++et)
        #pragma unroll
        for (int nt = 0; nt < 4; ++nt)
            acc[et][nt] = (f32x4){0.f, 0.f, 0.f, 0.f};

    #pragma unroll
    for (int ks = 0; ks < 4; ++ks) {
        short8 afr[4];
        #pragma unroll
        for (int et = 0; et < 4; ++et)
            afr[et] = *(const short8*)(sRow + (((ks * 4 + lg) * 64) + et * 16 + lm) * 16);
        #pragma unroll
        for (int nt = 0; nt < 4; ++nt) {
            const size_t wb = (size_t)(c0 + nt * 16 + lm) * C_DIM + ks * 32 + lg * 8;
            const short8 bh = *(const short8*)(whi + wb);
            const short8 bl = *(const short8*)(wlo + wb);
            #pragma unroll
            for (int et = 0; et < 4; ++et) {
                acc[et][nt] = __builtin_amdgcn_mfma_f32_16x16x32_bf16(afr[et], bh, acc[et][nt], 0, 0, 0);
                acc[et][nt] = __builtin_amdgcn_mfma_f32_16x16x32_bf16(afr[et], bl, acc[et][nt], 0, 0, 0);
            }
        }
    }

    // store ctx[r][c][e] bf16 (8B per lane per tile), overwrites the staged V rows
    #pragma unroll
    for (int et = 0; et < 4; ++et)
        #pragma unroll
        for (int nt = 0; nt < 4; ++nt) {
            const uint32_t u0 = (uint32_t)bfbits(acc[et][nt][0]) | ((uint32_t)bfbits(acc[et][nt][1]) << 16);
            const uint32_t u1 = (uint32_t)bfbits(acc[et][nt][2]) | ((uint32_t)bfbits(acc[et][nt][3]) << 16);
            const size_t bo = gr * 16384 + (size_t)(c0 + nt * 16 + lm) * 128 + (size_t)(et * 16 + lg * 4) * 2;
            *(uint2*)((char*)buf + bo) = make_uint2(u0, u1);
        }
}

// ---------- K3: out = P2 . relu(P1 @ ctx + pb1) + pb2, MFMA. M=r, N=f, K=e ----------
__global__ __launch_bounds__(256) void k3_out(
        const uint32_t* __restrict__ buf, const unsigned short* __restrict__ P1hi,
        const unsigned short* __restrict__ P1lo, const float* __restrict__ pb1,
        const float* __restrict__ P2, const float* __restrict__ pb2,
        float* __restrict__ out, int rowOff) {
    const int t = threadIdx.x;
    const int lane = t & 63, wv = t >> 6;
    const int lm = lane & 15, lg = lane >> 4;
    const int c = blockIdx.x;
    const int r0 = blockIdx.y * 64 + wv * 16;   // chunk-local

    float pb1r[4], p2r[4];
    #pragma unroll
    for (int nt = 0; nt < 4; ++nt) {
        pb1r[nt] = pb1[(size_t)c * 64 + nt * 16 + lm];
        p2r[nt]  = P2[(size_t)c * 64 + nt * 16 + lm];
    }

    f32x4 acc[4];
    #pragma unroll
    for (int nt = 0; nt < 4; ++nt) acc[nt] = (f32x4){0.f, 0.f, 0.f, 0.f};

    #pragma unroll
    for (int ks = 0; ks < 2; ++ks) {
        const short8 a = *(const short8*)((const char*)buf +
            (size_t)(r0 + lm) * 16384 + (size_t)c * 128 + (size_t)(ks * 32 + lg * 8) * 2);
        #pragma unroll
        for (int nt = 0; nt < 4; ++nt) {
            const size_t wb = ((size_t)c * 64 + nt * 16 + lm) * 64 + ks * 32 + lg * 8;
            const short8 bh = *(const short8*)(P1hi + wb);
            const short8 bl = *(const short8*)(P1lo + wb);
            acc[nt] = __builtin_amdgcn_mfma_f32_16x16x32_bf16(a, bh, acc[nt], 0, 0, 0);
            acc[nt] = __builtin_amdgcn_mfma_f32_16x16x32_bf16(a, bl, acc[nt], 0, 0, 0);
        }
    }

    const float pb2c = pb2[c];
    #pragma unroll
    for (int i = 0; i < 4; ++i) {
        float p = 0.f;
        #pragma unroll
        for (int nt = 0; nt < 4; ++nt)
            p = fmaf(fmaxf(acc[nt][i] + pb1r[nt], 0.f), p2r[nt], p);
        p += __shfl_xor(p, 1); p += __shfl_xor(p, 2);
        p += __shfl_xor(p, 4); p += __shfl_xor(p, 8);
        if (lm == 0)
            out[(size_t)(rowOff + r0 + lg * 4 + i) * C_DIM + c] = p + pb2c;
    }
}

// ---------- host ----------
extern "C" void kernel_launch(void* const* d_in, const int* in_sizes, int n_in,
                              void* d_out, int out_size, void* d_ws, size_t ws_size,
                              hipStream_t stream) {
    const float* samples = (const float*)d_in[0];
    const float* W1  = (const float*)d_in[1];
    const float* b1  = (const float*)d_in[2];
    const float* W2  = (const float*)d_in[3];
    const float* b2  = (const float*)d_in[4];
    const float* q   = (const float*)d_in[5];
    const float* P1  = (const float*)d_in[6];
    const float* pb1 = (const float*)d_in[7];
    const float* P2  = (const float*)d_in[8];
    const float* pb2 = (const float*)d_in[9];
    float* out = (float*)d_out;

    char* ws = (char*)d_ws;
    unsigned short* whi  = (unsigned short*)ws;                       // 32KB
    unsigned short* wlo  = (unsigned short*)(ws + 32768);             // 32KB
    unsigned short* W2hi = (unsigned short*)(ws + 65536);             // 1MB
    unsigned short* W2lo = (unsigned short*)(ws + 65536 + 1048576);   // 1MB
    unsigned short* P1hi = (unsigned short*)(ws + 65536 + 2097152);   // 1MB
    unsigned short* P1lo = (unsigned short*)(ws + 65536 + 3145728);   // 1MB
    uint32_t* buf = (uint32_t*)(ws + 65536 + 4194304);                // V/ctx, 16KB per row

    const size_t head = 65536 + 4194304;
    size_t avail = (ws_size > head) ? ws_size - head : 0;
    long maxRows = (long)(avail / ((size_t)C_DIM * E_DIM * 2));
    maxRows = (maxRows / 256) * 256;
    if (maxRows > B_DIM) maxRows = B_DIM;
    if (maxRows < 256) maxRows = 256;

    k0_softmax<<<dim3(C_DIM), dim3(C_DIM), 0, stream>>>(q, whi, wlo);
    kP_split<<<dim3(512), 256, 0, stream>>>(W2, W2hi, W2lo);   // 524288 floats / 4 / 256
    kP_split<<<dim3(512), 256, 0, stream>>>(P1, P1hi, P1lo);

    for (int off = 0; off < B_DIM; off += (int)maxRows) {
        const int rows = (int)(((long)(B_DIM - off) < maxRows) ? (long)(B_DIM - off) : maxRows);
        k1_value<<<dim3(rows / 64, 16), 512, 0, stream>>>(samples, W1, b1, W2hi, W2lo, b2, buf, off);
        k2_ctx<<<dim3(rows / 2), 256, 0, stream>>>(whi, wlo, buf);
        k3_out<<<dim3(C_DIM, rows / 64), 256, 0, stream>>>(buf, P1hi, P1lo, pb1, P2, pb2, out, off);
    }
}

// Round 3
// 285.126 us; speedup vs baseline: 2.6442x; 1.2323x over previous
//
#include <hip/hip_runtime.h>
#include <hip/hip_bf16.h>
#include <cstdint>

#define C_DIM 128
#define E_DIM 64
#define B_DIM 8192

typedef __attribute__((ext_vector_type(8))) short short8;
typedef __attribute__((ext_vector_type(4))) float f32x4;

union Frag8 { short8 v; short s[8]; uint32_t u[4]; };

__device__ __forceinline__ unsigned short bfbits(float x) {
    union { __hip_bfloat16 h; unsigned short u; } cv;
    cv.h = __float2bfloat16(x);
    return cv.u;
}
__device__ __forceinline__ float bits2f(unsigned short b) {
    return __uint_as_float(((uint32_t)b) << 16);
}

// ---------- K0: w = softmax(q,axis=1), zero diag, split hi/lo bf16, layout [c][n] ----------
__global__ __launch_bounds__(128) void k0_softmax(const float* __restrict__ q,
                                                  unsigned short* __restrict__ whi,
                                                  unsigned short* __restrict__ wlo) {
    const int c = blockIdx.x;
    const int t = threadIdx.x;            // n
    __shared__ float redM[2], redS[2];
    float v = q[c * C_DIM + t];
    float m = v;
    #pragma unroll
    for (int o = 32; o > 0; o >>= 1) m = fmaxf(m, __shfl_xor(m, o));
    if ((t & 63) == 0) redM[t >> 6] = m;
    __syncthreads();
    m = fmaxf(redM[0], redM[1]);
    float e = expf(v - m);
    float s = e;
    #pragma unroll
    for (int o = 32; o > 0; o >>= 1) s += __shfl_xor(s, o);
    if ((t & 63) == 0) redS[t >> 6] = s;
    __syncthreads();
    s = redS[0] + redS[1];
    float w = e / s;
    if (t == c) w = 0.f;                  // zero diagonal AFTER softmax
    unsigned short hb = bfbits(w);
    whi[c * C_DIM + t] = hb;
    wlo[c * C_DIM + t] = bfbits(w - bits2f(hb));
}

// ---------- KP: elementwise hi/lo bf16 split of a f32 weight tensor ----------
__global__ __launch_bounds__(256) void kP_split(const float* __restrict__ src,
                                                unsigned short* __restrict__ hi,
                                                unsigned short* __restrict__ lo) {
    const int i = blockIdx.x * 256 + threadIdx.x;   // index in float4 units
    const float4 v = ((const float4*)src)[i];
    float f[4] = {v.x, v.y, v.z, v.w};
    unsigned short h[4], l[4];
    #pragma unroll
    for (int j = 0; j < 4; ++j) {
        h[j] = bfbits(f[j]);
        l[j] = bfbits(f[j] - bits2f(h[j]));
    }
    ((ushort4*)hi)[i] = make_ushort4(h[0], h[1], h[2], h[3]);
    ((ushort4*)lo)[i] = make_ushort4(l[0], l[1], l[2], l[3]);
}

// ---------- K1: value MLP + L2 norm, MFMA. Output V[r][n8][e][8n] bf16 ----------
// block = 64 rows x 8 columns, 8 waves (1 column each). D: m=r, n=f.
__global__ __launch_bounds__(512) void k1_value(
        const float* __restrict__ samples, const float* __restrict__ W1,
        const float* __restrict__ b1, const unsigned short* __restrict__ W2hi,
        const unsigned short* __restrict__ W2lo, const float* __restrict__ b2,
        uint32_t* __restrict__ vbuf, int rowOff) {
    __shared__ unsigned short sOut[64 * 64 * 8];   // [r][f][c_local], 64KB, XOR-swizzled
    const int t = threadIdx.x;
    const int rt = blockIdx.x, cg = blockIdx.y;
    const int r0 = rt * 64;
    const int cl = t >> 6;                 // wave = local column
    const int lane = t & 63;
    const int lm = lane & 15, lg = lane >> 4;
    const int c = cg * 8 + cl;

    // per-lane scalars: samples for the 4 M-tiles this lane's A-rows need
    float sv[4];
    #pragma unroll
    for (int mt = 0; mt < 4; ++mt)
        sv[mt] = samples[(size_t)(rowOff + r0 + mt * 16 + lm) * C_DIM + c];

    // per-lane W1/b1 slices (k-contiguous 8 elems per k-step)
    float w1r[2][8], b1r[2][8];
    #pragma unroll
    for (int ks = 0; ks < 2; ++ks) {
        const float* wp = W1 + (size_t)c * 64 + ks * 32 + lg * 8;
        const float* bp = b1 + (size_t)c * 64 + ks * 32 + lg * 8;
        #pragma unroll
        for (int j = 0; j < 8; ++j) { w1r[ks][j] = wp[j]; b1r[ks][j] = bp[j]; }
    }
    float b2r[4];
    #pragma unroll
    for (int nt = 0; nt < 4; ++nt) b2r[nt] = b2[(size_t)c * 64 + nt * 16 + lm];

    f32x4 acc[4][4];
    #pragma unroll
    for (int mt = 0; mt < 4; ++mt)
        #pragma unroll
        for (int nt = 0; nt < 4; ++nt)
            acc[mt][nt] = (f32x4){0.f, 0.f, 0.f, 0.f};

    #pragma unroll
    for (int ks = 0; ks < 2; ++ks) {
        short8 afr[4];
        #pragma unroll
        for (int mt = 0; mt < 4; ++mt) {
            Frag8 af;
            #pragma unroll
            for (int j = 0; j < 8; ++j)
                af.s[j] = (short)bfbits(fmaxf(fmaf(sv[mt], w1r[ks][j], b1r[ks][j]), 0.f));
            afr[mt] = af.v;
        }
        #pragma unroll
        for (int nt = 0; nt < 4; ++nt) {
            const size_t wb = ((size_t)c * 64 + nt * 16 + lm) * 64 + ks * 32 + lg * 8;
            const short8 bh = *(const short8*)(W2hi + wb);
            const short8 bl = *(const short8*)(W2lo + wb);
            #pragma unroll
            for (int mt = 0; mt < 4; ++mt) {
                acc[mt][nt] = __builtin_amdgcn_mfma_f32_16x16x32_bf16(afr[mt], bh, acc[mt][nt], 0, 0, 0);
                acc[mt][nt] = __builtin_amdgcn_mfma_f32_16x16x32_bf16(afr[mt], bl, acc[mt][nt], 0, 0, 0);
            }
        }
    }

    // add b2, sum of squares over f (lane-local over nt, butterfly over lm lanes)
    float rsc[4][4];
    #pragma unroll
    for (int mt = 0; mt < 4; ++mt)
        #pragma unroll
        for (int i = 0; i < 4; ++i) {
            float s2 = 0.f;
            #pragma unroll
            for (int nt = 0; nt < 4; ++nt) {
                float vv = acc[mt][nt][i] + b2r[nt];
                acc[mt][nt][i] = vv;
                s2 = fmaf(vv, vv, s2);
            }
            s2 += __shfl_xor(s2, 1); s2 += __shfl_xor(s2, 2);
            s2 += __shfl_xor(s2, 4); s2 += __shfl_xor(s2, 8);
            rsc[mt][i] = 1.f / fmaxf(sqrtf(s2), 1e-12f);
        }

    // repack into LDS [r][f][c_local] bf16, XOR-swizzled by row
    #pragma unroll
    for (int mt = 0; mt < 4; ++mt)
        #pragma unroll
        for (int i = 0; i < 4; ++i) {
            const int r = mt * 16 + lg * 4 + i;
            const uint32_t rowbase = (uint32_t)r * 1024u;
            const uint32_t swz = (uint32_t)(r & 7) << 4;
            #pragma unroll
            for (int nt = 0; nt < 4; ++nt) {
                const int f = nt * 16 + lm;
                const uint32_t bo = (rowbase + (uint32_t)f * 16u + (uint32_t)cl * 2u) ^ swz;
                *(unsigned short*)((char*)sOut + bo) = bfbits(acc[mt][nt][i] * rsc[mt][i]);
            }
        }
    __syncthreads();

    // coalesced writeout: V[r][n8=cg][f][8n] -> per (r): 1KB contiguous
    #pragma unroll
    for (int it = 0; it < 8; ++it) {
        const int chunk = t + it * 512;
        const int r = chunk >> 6, f = chunk & 63;
        const uint32_t lb = ((uint32_t)r * 1024u + (uint32_t)f * 16u) ^ ((uint32_t)(r & 7) << 4);
        const uint4 val = *(const uint4*)((const char*)sOut + lb);
        ((uint4*)vbuf)[((size_t)(r0 + r) * 16 + cg) * 64 + f] = val;
    }
}

// ---------- K2: ctx[r][c][e] = sum_n w[c,n] V[r,n,e], MFMA, in-place over V ----------
// block = 2 rows, 4 waves: wave = (row, c-half). M=e, N=c, K=n.
__global__ __launch_bounds__(256) void k2_ctx(
        const unsigned short* __restrict__ whi, const unsigned short* __restrict__ wlo,
        uint32_t* __restrict__ buf) {
    __shared__ uint4 sV4[2048];            // 32KB = two consecutive V rows (linear)
    const int t = threadIdx.x;
    const int lane = t & 63, wv = t >> 6;
    const int lm = lane & 15, lg = lane >> 4;
    const size_t gr0 = (size_t)blockIdx.x * 2;

    const uint4* gsrc = (const uint4*)((const char*)buf + gr0 * 16384);
    #pragma unroll
    for (int i = 0; i < 8; ++i) sV4[t + i * 256] = gsrc[t + i * 256];
    __syncthreads();

    const int rl = wv >> 1, ch = wv & 1;
    const size_t gr = gr0 + rl;
    const char* sRow = (const char*)sV4 + rl * 16384;
    const int c0 = ch * 64;

    f32x4 acc[4][4];                       // [et][nt]
    #pragma unroll
    for (int et = 0; et < 4; ++et)
        #pragma unroll
        for (int nt = 0; nt < 4; ++nt)
            acc[et][nt] = (f32x4){0.f, 0.f, 0.f, 0.f};

    #pragma unroll
    for (int ks = 0; ks < 4; ++ks) {
        short8 afr[4];
        #pragma unroll
        for (int et = 0; et < 4; ++et)
            afr[et] = *(const short8*)(sRow + (((ks * 4 + lg) * 64) + et * 16 + lm) * 16);
        #pragma unroll
        for (int nt = 0; nt < 4; ++nt) {
            const size_t wb = (size_t)(c0 + nt * 16 + lm) * C_DIM + ks * 32 + lg * 8;
            const short8 bh = *(const short8*)(whi + wb);
            const short8 bl = *(const short8*)(wlo + wb);
            #pragma unroll
            for (int et = 0; et < 4; ++et) {
                acc[et][nt] = __builtin_amdgcn_mfma_f32_16x16x32_bf16(afr[et], bh, acc[et][nt], 0, 0, 0);
                acc[et][nt] = __builtin_amdgcn_mfma_f32_16x16x32_bf16(afr[et], bl, acc[et][nt], 0, 0, 0);
            }
        }
    }

    // store ctx[r][c][e] bf16 (8B per lane per tile), overwrites the staged V rows
    #pragma unroll
    for (int et = 0; et < 4; ++et)
        #pragma unroll
        for (int nt = 0; nt < 4; ++nt) {
            const uint32_t u0 = (uint32_t)bfbits(acc[et][nt][0]) | ((uint32_t)bfbits(acc[et][nt][1]) << 16);
            const uint32_t u1 = (uint32_t)bfbits(acc[et][nt][2]) | ((uint32_t)bfbits(acc[et][nt][3]) << 16);
            const size_t bo = gr * 16384 + (size_t)(c0 + nt * 16 + lm) * 128 + (size_t)(et * 16 + lg * 4) * 2;
            *(uint2*)((char*)buf + bo) = make_uint2(u0, u1);
        }
}

// ---------- K3: out = P2 . relu(P1 @ ctx + pb1) + pb2, MFMA, LDS-staged ----------
// block = 64 rows x 8 columns, 8 waves (1 column each). M=r (4 tiles), N=f, K=e.
__global__ __launch_bounds__(512) void k3_out(
        const uint32_t* __restrict__ buf, const unsigned short* __restrict__ P1hi,
        const unsigned short* __restrict__ P1lo, const float* __restrict__ pb1,
        const float* __restrict__ P2, const float* __restrict__ pb2,
        float* __restrict__ out, int rowOff) {
    __shared__ char sC[64 * 1024];          // [r][c_local][e] bf16, 64KB, XOR-swizzled
    const int t = threadIdx.x;
    const int cg = blockIdx.x;              // 16 groups of 8 columns
    const int r0 = blockIdx.y * 64;         // chunk-local
    const int lane = t & 63, wv = t >> 6;
    const int lm = lane & 15, lg = lane >> 4;
    const int cl = wv;
    const int c = cg * 8 + cl;

    // stage ctx[r0..r0+63][cg*8..+8][all e] coalesced: 1KB contiguous per row
    {
        const int rr = t >> 6;              // 8 rows per pass
        const int inner = t & 63;           // 16B chunk within the 1KB c-window
        #pragma unroll
        for (int p = 0; p < 8; ++p) {
            const int r = p * 8 + rr;
            const uint4 val = *(const uint4*)((const char*)buf +
                (size_t)(r0 + r) * 16384 + (size_t)cg * 1024 + (size_t)inner * 16);
            const uint32_t bo = ((uint32_t)r * 1024u + (uint32_t)inner * 16u) ^ ((uint32_t)(r & 7) << 4);
            *(uint4*)(sC + bo) = val;
        }
    }
    __syncthreads();

    float pb1r[4], p2r[4];
    #pragma unroll
    for (int nt = 0; nt < 4; ++nt) {
        pb1r[nt] = pb1[(size_t)c * 64 + nt * 16 + lm];
        p2r[nt]  = P2[(size_t)c * 64 + nt * 16 + lm];
    }
    const float pb2c = pb2[c];

    f32x4 acc[4][4];                        // [mt][nt]
    #pragma unroll
    for (int mt = 0; mt < 4; ++mt)
        #pragma unroll
        for (int nt = 0; nt < 4; ++nt)
            acc[mt][nt] = (f32x4){0.f, 0.f, 0.f, 0.f};

    #pragma unroll
    for (int ks = 0; ks < 2; ++ks) {
        short8 a[4];
        #pragma unroll
        for (int mt = 0; mt < 4; ++mt) {
            const int rl = mt * 16 + lm;
            const uint32_t bo = ((uint32_t)rl * 1024u + (uint32_t)cl * 128u +
                                 (uint32_t)ks * 64u + (uint32_t)lg * 16u) ^ ((uint32_t)(rl & 7) << 4);
            a[mt] = *(const short8*)(sC + bo);
        }
        #pragma unroll
        for (int nt = 0; nt < 4; ++nt) {
            const size_t wb = ((size_t)c * 64 + nt * 16 + lm) * 64 + ks * 32 + lg * 8;
            const short8 bh = *(const short8*)(P1hi + wb);
            const short8 bl = *(const short8*)(P1lo + wb);
            #pragma unroll
            for (int mt = 0; mt < 4; ++mt) {
                acc[mt][nt] = __builtin_amdgcn_mfma_f32_16x16x32_bf16(a[mt], bh, acc[mt][nt], 0, 0, 0);
                acc[mt][nt] = __builtin_amdgcn_mfma_f32_16x16x32_bf16(a[mt], bl, acc[mt][nt], 0, 0, 0);
            }
        }
    }

    // epilogue: relu, dot with P2 over f (lane-local nt + butterfly over lm), store
    #pragma unroll
    for (int mt = 0; mt < 4; ++mt)
        #pragma unroll
        for (int i = 0; i < 4; ++i) {
            float p = 0.f;
            #pragma unroll
            for (int nt = 0; nt < 4; ++nt)
                p = fmaf(fmaxf(acc[mt][nt][i] + pb1r[nt], 0.f), p2r[nt], p);
            p += __shfl_xor(p, 1); p += __shfl_xor(p, 2);
            p += __shfl_xor(p, 4); p += __shfl_xor(p, 8);
            if (lm == 0)
                out[(size_t)(rowOff + r0 + mt * 16 + lg * 4 + i) * C_DIM + c] = p + pb2c;
        }
}

// ---------- host ----------
extern "C" void kernel_launch(void* const* d_in, const int* in_sizes, int n_in,
                              void* d_out, int out_size, void* d_ws, size_t ws_size,
                              hipStream_t stream) {
    const float* samples = (const float*)d_in[0];
    const float* W1  = (const float*)d_in[1];
    const float* b1  = (const float*)d_in[2];
    const float* W2  = (const float*)d_in[3];
    const float* b2  = (const float*)d_in[4];
    const float* q   = (const float*)d_in[5];
    const float* P1  = (const float*)d_in[6];
    const float* pb1 = (const float*)d_in[7];
    const float* P2  = (const float*)d_in[8];
    const float* pb2 = (const float*)d_in[9];
    float* out = (float*)d_out;

    char* ws = (char*)d_ws;
    unsigned short* whi  = (unsigned short*)ws;                       // 32KB
    unsigned short* wlo  = (unsigned short*)(ws + 32768);             // 32KB
    unsigned short* W2hi = (unsigned short*)(ws + 65536);             // 1MB
    unsigned short* W2lo = (unsigned short*)(ws + 65536 + 1048576);   // 1MB
    unsigned short* P1hi = (unsigned short*)(ws + 65536 + 2097152);   // 1MB
    unsigned short* P1lo = (unsigned short*)(ws + 65536 + 3145728);   // 1MB
    uint32_t* buf = (uint32_t*)(ws + 65536 + 4194304);                // V/ctx, 16KB per row

    const size_t head = 65536 + 4194304;
    size_t avail = (ws_size > head) ? ws_size - head : 0;
    long maxRows = (long)(avail / ((size_t)C_DIM * E_DIM * 2));
    maxRows = (maxRows / 256) * 256;
    if (maxRows > B_DIM) maxRows = B_DIM;
    if (maxRows < 256) maxRows = 256;

    k0_softmax<<<dim3(C_DIM), dim3(C_DIM), 0, stream>>>(q, whi, wlo);
    kP_split<<<dim3(512), 256, 0, stream>>>(W2, W2hi, W2lo);   // 524288 floats / 4 / 256
    kP_split<<<dim3(512), 256, 0, stream>>>(P1, P1hi, P1lo);

    for (int off = 0; off < B_DIM; off += (int)maxRows) {
        const int rows = (int)(((long)(B_DIM - off) < maxRows) ? (long)(B_DIM - off) : maxRows);
        k1_value<<<dim3(rows / 64, 16), 512, 0, stream>>>(samples, W1, b1, W2hi, W2lo, b2, buf, off);
        k2_ctx<<<dim3(rows / 2), 256, 0, stream>>>(whi, wlo, buf);
        k3_out<<<dim3(16, rows / 64), 512, 0, stream>>>(buf, P1hi, P1lo, pb1, P2, pb2, out, off);
    }
}

// Round 4
// 265.738 us; speedup vs baseline: 2.8371x; 1.0730x over previous
//
#include <hip/hip_runtime.h>
#include <hip/hip_bf16.h>
#include <cstdint>

#define C_DIM 128
#define E_DIM 64
#define B_DIM 8192

typedef __attribute__((ext_vector_type(8))) short short8;
typedef __attribute__((ext_vector_type(4))) float f32x4;

union Frag8 { short8 v; short s[8]; uint32_t u[4]; };

__device__ __forceinline__ unsigned short bfbits(float x) {
    union { __hip_bfloat16 h; unsigned short u; } cv;
    cv.h = __float2bfloat16(x);
    return cv.u;
}
__device__ __forceinline__ float bits2f(unsigned short b) {
    return __uint_as_float(((uint32_t)b) << 16);
}

// ---------- K0: w = softmax(q,axis=1), zero diag, split hi/lo bf16, layout [c][n] ----------
__global__ __launch_bounds__(128) void k0_softmax(const float* __restrict__ q,
                                                  unsigned short* __restrict__ whi,
                                                  unsigned short* __restrict__ wlo) {
    const int c = blockIdx.x;
    const int t = threadIdx.x;            // n
    __shared__ float redM[2], redS[2];
    float v = q[c * C_DIM + t];
    float m = v;
    #pragma unroll
    for (int o = 32; o > 0; o >>= 1) m = fmaxf(m, __shfl_xor(m, o));
    if ((t & 63) == 0) redM[t >> 6] = m;
    __syncthreads();
    m = fmaxf(redM[0], redM[1]);
    float e = expf(v - m);
    float s = e;
    #pragma unroll
    for (int o = 32; o > 0; o >>= 1) s += __shfl_xor(s, o);
    if ((t & 63) == 0) redS[t >> 6] = s;
    __syncthreads();
    s = redS[0] + redS[1];
    float w = e / s;
    if (t == c) w = 0.f;                  // zero diagonal AFTER softmax
    unsigned short hb = bfbits(w);
    whi[c * C_DIM + t] = hb;
    wlo[c * C_DIM + t] = bfbits(w - bits2f(hb));
}

// ---------- KP: elementwise hi/lo bf16 split of a f32 weight tensor ----------
__global__ __launch_bounds__(256) void kP_split(const float* __restrict__ src,
                                                unsigned short* __restrict__ hi,
                                                unsigned short* __restrict__ lo) {
    const int i = blockIdx.x * 256 + threadIdx.x;   // index in float4 units
    const float4 v = ((const float4*)src)[i];
    float f[4] = {v.x, v.y, v.z, v.w};
    unsigned short h[4], l[4];
    #pragma unroll
    for (int j = 0; j < 4; ++j) {
        h[j] = bfbits(f[j]);
        l[j] = bfbits(f[j] - bits2f(h[j]));
    }
    ((ushort4*)hi)[i] = make_ushort4(h[0], h[1], h[2], h[3]);
    ((ushort4*)lo)[i] = make_ushort4(l[0], l[1], l[2], l[3]);
}

// ---------- K1: value MLP + L2 norm, MFMA. Output V[r][n8][e][8n] bf16 ----------
// block = 64 rows x 8 columns, 8 waves (1 column each). D: m=r, n=f.
__global__ __launch_bounds__(512) void k1_value(
        const float* __restrict__ samples, const float* __restrict__ W1,
        const float* __restrict__ b1, const unsigned short* __restrict__ W2hi,
        const unsigned short* __restrict__ W2lo, const float* __restrict__ b2,
        uint32_t* __restrict__ vbuf, int rowOff) {
    __shared__ unsigned short sOut[64 * 64 * 8];   // [r][f][c_local], 64KB, XOR-swizzled
    const int t = threadIdx.x;
    const int rt = blockIdx.x, cg = blockIdx.y;
    const int r0 = rt * 64;
    const int cl = t >> 6;                 // wave = local column
    const int lane = t & 63;
    const int lm = lane & 15, lg = lane >> 4;
    const int c = cg * 8 + cl;

    // per-lane scalars: samples for the 4 M-tiles this lane's A-rows need
    float sv[4];
    #pragma unroll
    for (int mt = 0; mt < 4; ++mt)
        sv[mt] = samples[(size_t)(rowOff + r0 + mt * 16 + lm) * C_DIM + c];

    // per-lane W1/b1 slices (k-contiguous 8 elems per k-step)
    float w1r[2][8], b1r[2][8];
    #pragma unroll
    for (int ks = 0; ks < 2; ++ks) {
        const float* wp = W1 + (size_t)c * 64 + ks * 32 + lg * 8;
        const float* bp = b1 + (size_t)c * 64 + ks * 32 + lg * 8;
        #pragma unroll
        for (int j = 0; j < 8; ++j) { w1r[ks][j] = wp[j]; b1r[ks][j] = bp[j]; }
    }
    float b2r[4];
    #pragma unroll
    for (int nt = 0; nt < 4; ++nt) b2r[nt] = b2[(size_t)c * 64 + nt * 16 + lm];

    f32x4 acc[4][4];
    #pragma unroll
    for (int mt = 0; mt < 4; ++mt)
        #pragma unroll
        for (int nt = 0; nt < 4; ++nt)
            acc[mt][nt] = (f32x4){0.f, 0.f, 0.f, 0.f};

    #pragma unroll
    for (int ks = 0; ks < 2; ++ks) {
        short8 afr[4];
        #pragma unroll
        for (int mt = 0; mt < 4; ++mt) {
            Frag8 af;
            #pragma unroll
            for (int j = 0; j < 8; ++j)
                af.s[j] = (short)bfbits(fmaxf(fmaf(sv[mt], w1r[ks][j], b1r[ks][j]), 0.f));
            afr[mt] = af.v;
        }
        #pragma unroll
        for (int nt = 0; nt < 4; ++nt) {
            const size_t wb = ((size_t)c * 64 + nt * 16 + lm) * 64 + ks * 32 + lg * 8;
            const short8 bh = *(const short8*)(W2hi + wb);
            const short8 bl = *(const short8*)(W2lo + wb);
            #pragma unroll
            for (int mt = 0; mt < 4; ++mt) {
                acc[mt][nt] = __builtin_amdgcn_mfma_f32_16x16x32_bf16(afr[mt], bh, acc[mt][nt], 0, 0, 0);
                acc[mt][nt] = __builtin_amdgcn_mfma_f32_16x16x32_bf16(afr[mt], bl, acc[mt][nt], 0, 0, 0);
            }
        }
    }

    // add b2, sum of squares over f (lane-local over nt, butterfly over lm lanes)
    float rsc[4][4];
    #pragma unroll
    for (int mt = 0; mt < 4; ++mt)
        #pragma unroll
        for (int i = 0; i < 4; ++i) {
            float s2 = 0.f;
            #pragma unroll
            for (int nt = 0; nt < 4; ++nt) {
                float vv = acc[mt][nt][i] + b2r[nt];
                acc[mt][nt][i] = vv;
                s2 = fmaf(vv, vv, s2);
            }
            s2 += __shfl_xor(s2, 1); s2 += __shfl_xor(s2, 2);
            s2 += __shfl_xor(s2, 4); s2 += __shfl_xor(s2, 8);
            rsc[mt][i] = 1.f / fmaxf(sqrtf(s2), 1e-12f);
        }

    // repack into LDS [r][f][c_local] bf16, XOR-swizzled by row
    #pragma unroll
    for (int mt = 0; mt < 4; ++mt)
        #pragma unroll
        for (int i = 0; i < 4; ++i) {
            const int r = mt * 16 + lg * 4 + i;
            const uint32_t rowbase = (uint32_t)r * 1024u;
            const uint32_t swz = (uint32_t)(r & 7) << 4;
            #pragma unroll
            for (int nt = 0; nt < 4; ++nt) {
                const int f = nt * 16 + lm;
                const uint32_t bo = (rowbase + (uint32_t)f * 16u + (uint32_t)cl * 2u) ^ swz;
                *(unsigned short*)((char*)sOut + bo) = bfbits(acc[mt][nt][i] * rsc[mt][i]);
            }
        }
    __syncthreads();

    // coalesced writeout: V[r][n8=cg][f][8n] -> per (r): 1KB contiguous
    #pragma unroll
    for (int it = 0; it < 8; ++it) {
        const int chunk = t + it * 512;
        const int r = chunk >> 6, f = chunk & 63;
        const uint32_t lb = ((uint32_t)r * 1024u + (uint32_t)f * 16u) ^ ((uint32_t)(r & 7) << 4);
        const uint4 val = *(const uint4*)((const char*)sOut + lb);
        ((uint4*)vbuf)[((size_t)(r0 + r) * 16 + cg) * 64 + f] = val;
    }
}

// ---------- K2: ctx[r][c][e] = sum_n w[c,n] V[r,n,e]  (separate output buffer) ----------
// block = 256 thr, 4 waves = (rg 0..1, ch 0..1); 4 rows/block, 2 rows/wave.
// w hi+lo staged once in LDS (XOR-swizzled); V A-frags streamed direct from global.
__global__ __launch_bounds__(256) void k2_ctx(
        const unsigned short* __restrict__ whi, const unsigned short* __restrict__ wlo,
        const uint32_t* __restrict__ vbuf, uint32_t* __restrict__ cbuf) {
    __shared__ char sW[65536];   // [hi 32K | lo 32K], 256 B per c-row, byte^=((c&7)<<4)
    const int t = threadIdx.x;
    const int lane = t & 63, wv = t >> 6;
    const int lm = lane & 15, lg = lane >> 4;

    #pragma unroll
    for (int i = 0; i < 8; ++i) {
        const int idx = t + i * 256;                       // 16B-unit index within 32KB
        const int c = idx >> 4;
        const uint32_t bo = (((uint32_t)idx * 16u) ^ (((uint32_t)c & 7u) << 4));
        *(uint4*)(sW + bo)         = ((const uint4*)whi)[idx];
        *(uint4*)(sW + 32768 + bo) = ((const uint4*)wlo)[idx];
    }
    __syncthreads();

    const int rg = wv >> 1, ch = wv & 1;
    const int c0 = ch * 64;
    const size_t rbase = (size_t)blockIdx.x * 4 + (size_t)rg * 2;

    #pragma unroll 1
    for (int rr = 0; rr < 2; ++rr) {
        const size_t r = rbase + rr;
        const char* vrow = (const char*)vbuf + (r << 14);

        short8 aA[4], aB[4];   // ks double-buffer (static names, rule #20)
        #pragma unroll
        for (int et = 0; et < 4; ++et)
            aA[et] = *(const short8*)(vrow + (0 * 4 + lg) * 1024 + (et * 16 + lm) * 16);

        f32x4 acc[4][4];       // [et][nt]
        #pragma unroll
        for (int et = 0; et < 4; ++et)
            #pragma unroll
            for (int nt = 0; nt < 4; ++nt)
                acc[et][nt] = (f32x4){0.f, 0.f, 0.f, 0.f};

#define K2_STEP(KS, ACUR, ANXT, PREFETCH)                                                  \
        {                                                                                  \
            if (PREFETCH) {                                                                \
                _Pragma("unroll")                                                          \
                for (int et = 0; et < 4; ++et)                                             \
                    ANXT[et] = *(const short8*)(vrow + ((KS + 1) * 4 + lg) * 1024 +        \
                                                (et * 16 + lm) * 16);                      \
            }                                                                              \
            _Pragma("unroll")                                                              \
            for (int nt = 0; nt < 4; ++nt) {                                               \
                const int cc = c0 + nt * 16 + lm;                                          \
                const uint32_t wb = (((uint32_t)cc * 256u +                                \
                                      (uint32_t)((KS) * 32 + lg * 8) * 2u) ^               \
                                     (((uint32_t)cc & 7u) << 4));                          \
                const short8 bh = *(const short8*)(sW + wb);                               \
                const short8 bl = *(const short8*)(sW + 32768 + wb);                       \
                _Pragma("unroll")                                                          \
                for (int et = 0; et < 4; ++et) {                                           \
                    acc[et][nt] = __builtin_amdgcn_mfma_f32_16x16x32_bf16(ACUR[et], bh,    \
                                                                 acc[et][nt], 0, 0, 0);    \
                    acc[et][nt] = __builtin_amdgcn_mfma_f32_16x16x32_bf16(ACUR[et], bl,    \
                                                                 acc[et][nt], 0, 0, 0);    \
                }                                                                          \
            }                                                                              \
        }
        K2_STEP(0, aA, aB, 1)
        K2_STEP(1, aB, aA, 1)
        K2_STEP(2, aA, aB, 1)
        K2_STEP(3, aB, aA, 0)
#undef K2_STEP

        // store ctx[r][c][e] bf16, 8 B per (et,nt) per lane
        char* crow = (char*)cbuf + (r << 14);
        #pragma unroll
        for (int et = 0; et < 4; ++et)
            #pragma unroll
            for (int nt = 0; nt < 4; ++nt) {
                const uint32_t u0 = (uint32_t)bfbits(acc[et][nt][0]) | ((uint32_t)bfbits(acc[et][nt][1]) << 16);
                const uint32_t u1 = (uint32_t)bfbits(acc[et][nt][2]) | ((uint32_t)bfbits(acc[et][nt][3]) << 16);
                *(uint2*)(crow + (size_t)(c0 + nt * 16 + lm) * 128 + (size_t)(et * 16 + lg * 4) * 2) =
                    make_uint2(u0, u1);
            }
    }
}

// ---------- K3: out = P2 . relu(P1 @ ctx + pb1) + pb2, MFMA, LDS-staged ----------
// block = 64 rows x 8 columns, 8 waves (1 column each). M=r (4 tiles), N=f, K=e.
__global__ __launch_bounds__(512) void k3_out(
        const uint32_t* __restrict__ cbuf, const unsigned short* __restrict__ P1hi,
        const unsigned short* __restrict__ P1lo, const float* __restrict__ pb1,
        const float* __restrict__ P2, const float* __restrict__ pb2,
        float* __restrict__ out, int rowOff) {
    __shared__ char sC[64 * 1024];          // [r][c_local][e] bf16, 64KB, XOR-swizzled
    const int t = threadIdx.x;
    const int cg = blockIdx.x;              // 16 groups of 8 columns
    const int r0 = blockIdx.y * 64;         // chunk-local
    const int lane = t & 63, wv = t >> 6;
    const int lm = lane & 15, lg = lane >> 4;
    const int cl = wv;
    const int c = cg * 8 + cl;

    // stage ctx[r0..r0+63][cg*8..+8][all e] coalesced: 1KB contiguous per row
    {
        const int rr = t >> 6;              // 8 rows per pass
        const int inner = t & 63;           // 16B chunk within the 1KB c-window
        #pragma unroll
        for (int p = 0; p < 8; ++p) {
            const int r = p * 8 + rr;
            const uint4 val = *(const uint4*)((const char*)cbuf +
                (size_t)(r0 + r) * 16384 + (size_t)cg * 1024 + (size_t)inner * 16);
            const uint32_t bo = ((uint32_t)r * 1024u + (uint32_t)inner * 16u) ^ ((uint32_t)(r & 7) << 4);
            *(uint4*)(sC + bo) = val;
        }
    }
    __syncthreads();

    float pb1r[4], p2r[4];
    #pragma unroll
    for (int nt = 0; nt < 4; ++nt) {
        pb1r[nt] = pb1[(size_t)c * 64 + nt * 16 + lm];
        p2r[nt]  = P2[(size_t)c * 64 + nt * 16 + lm];
    }
    const float pb2c = pb2[c];

    f32x4 acc[4][4];                        // [mt][nt]
    #pragma unroll
    for (int mt = 0; mt < 4; ++mt)
        #pragma unroll
        for (int nt = 0; nt < 4; ++nt)
            acc[mt][nt] = (f32x4){0.f, 0.f, 0.f, 0.f};

    #pragma unroll
    for (int ks = 0; ks < 2; ++ks) {
        short8 a[4];
        #pragma unroll
        for (int mt = 0; mt < 4; ++mt) {
            const int rl = mt * 16 + lm;
            const uint32_t bo = ((uint32_t)rl * 1024u + (uint32_t)cl * 128u +
                                 (uint32_t)ks * 64u + (uint32_t)lg * 16u) ^ ((uint32_t)(rl & 7) << 4);
            a[mt] = *(const short8*)(sC + bo);
        }
        #pragma unroll
        for (int nt = 0; nt < 4; ++nt) {
            const size_t wb = ((size_t)c * 64 + nt * 16 + lm) * 64 + ks * 32 + lg * 8;
            const short8 bh = *(const short8*)(P1hi + wb);
            const short8 bl = *(const short8*)(P1lo + wb);
            #pragma unroll
            for (int mt = 0; mt < 4; ++mt) {
                acc[mt][nt] = __builtin_amdgcn_mfma_f32_16x16x32_bf16(a[mt], bh, acc[mt][nt], 0, 0, 0);
                acc[mt][nt] = __builtin_amdgcn_mfma_f32_16x16x32_bf16(a[mt], bl, acc[mt][nt], 0, 0, 0);
            }
        }
    }

    // epilogue: relu, dot with P2 over f (lane-local nt + butterfly over lm), store
    #pragma unroll
    for (int mt = 0; mt < 4; ++mt)
        #pragma unroll
        for (int i = 0; i < 4; ++i) {
            float p = 0.f;
            #pragma unroll
            for (int nt = 0; nt < 4; ++nt)
                p = fmaf(fmaxf(acc[mt][nt][i] + pb1r[nt], 0.f), p2r[nt], p);
            p += __shfl_xor(p, 1); p += __shfl_xor(p, 2);
            p += __shfl_xor(p, 4); p += __shfl_xor(p, 8);
            if (lm == 0)
                out[(size_t)(rowOff + r0 + mt * 16 + lg * 4 + i) * C_DIM + c] = p + pb2c;
        }
}

// ---------- host ----------
extern "C" void kernel_launch(void* const* d_in, const int* in_sizes, int n_in,
                              void* d_out, int out_size, void* d_ws, size_t ws_size,
                              hipStream_t stream) {
    const float* samples = (const float*)d_in[0];
    const float* W1  = (const float*)d_in[1];
    const float* b1  = (const float*)d_in[2];
    const float* W2  = (const float*)d_in[3];
    const float* b2  = (const float*)d_in[4];
    const float* q   = (const float*)d_in[5];
    const float* P1  = (const float*)d_in[6];
    const float* pb1 = (const float*)d_in[7];
    const float* P2  = (const float*)d_in[8];
    const float* pb2 = (const float*)d_in[9];
    float* out = (float*)d_out;

    char* ws = (char*)d_ws;
    unsigned short* whi  = (unsigned short*)ws;                       // 32KB
    unsigned short* wlo  = (unsigned short*)(ws + 32768);             // 32KB
    unsigned short* W2hi = (unsigned short*)(ws + 65536);             // 1MB
    unsigned short* W2lo = (unsigned short*)(ws + 65536 + 1048576);   // 1MB
    unsigned short* P1hi = (unsigned short*)(ws + 65536 + 2097152);   // 1MB
    unsigned short* P1lo = (unsigned short*)(ws + 65536 + 3145728);   // 1MB
    const size_t head = 65536 + 4194304;

    // two regions: V and ctx, each maxRows*16KB
    size_t avail = (ws_size > head) ? ws_size - head : 0;
    long maxRows = (long)(avail / ((size_t)2 * C_DIM * E_DIM * 2));
    maxRows = (maxRows / 256) * 256;
    if (maxRows > B_DIM) maxRows = B_DIM;
    if (maxRows < 256) maxRows = 256;

    uint32_t* vbuf = (uint32_t*)(ws + head);
    uint32_t* cbuf = (uint32_t*)(ws + head + (size_t)maxRows * 16384);

    k0_softmax<<<dim3(C_DIM), dim3(C_DIM), 0, stream>>>(q, whi, wlo);
    kP_split<<<dim3(512), 256, 0, stream>>>(W2, W2hi, W2lo);   // 524288 floats / 4 / 256
    kP_split<<<dim3(512), 256, 0, stream>>>(P1, P1hi, P1lo);

    for (int off = 0; off < B_DIM; off += (int)maxRows) {
        const int rows = (int)(((long)(B_DIM - off) < maxRows) ? (long)(B_DIM - off) : maxRows);
        k1_value<<<dim3(rows / 64, 16), 512, 0, stream>>>(samples, W1, b1, W2hi, W2lo, b2, vbuf, off);
        k2_ctx<<<dim3(rows / 4), 256, 0, stream>>>(whi, wlo, vbuf, cbuf);
        k3_out<<<dim3(16, rows / 64), 512, 0, stream>>>(cbuf, P1hi, P1lo, pb1, P2, pb2, out, off);
    }
}

// Round 5
// 244.647 us; speedup vs baseline: 3.0817x; 1.0862x over previous
//
#include <hip/hip_runtime.h>
#include <hip/hip_bf16.h>
#include <cstdint>

#define C_DIM 128
#define E_DIM 64
#define B_DIM 8192

typedef __attribute__((ext_vector_type(8))) short short8;
typedef __attribute__((ext_vector_type(4))) float f32x4;

union Frag8 { short8 v; short s[8]; uint32_t u[4]; };

__device__ __forceinline__ unsigned short bfbits(float x) {
    union { __hip_bfloat16 h; unsigned short u; } cv;
    cv.h = __float2bfloat16(x);
    return cv.u;
}
__device__ __forceinline__ float bits2f(unsigned short b) {
    return __uint_as_float(((uint32_t)b) << 16);
}

// ---------- K0: w = softmax(q,axis=1), zero diag, split hi/lo bf16, layout [c][n] ----------
__global__ __launch_bounds__(128) void k0_softmax(const float* __restrict__ q,
                                                  unsigned short* __restrict__ whi,
                                                  unsigned short* __restrict__ wlo) {
    const int c = blockIdx.x;
    const int t = threadIdx.x;            // n
    __shared__ float redM[2], redS[2];
    float v = q[c * C_DIM + t];
    float m = v;
    #pragma unroll
    for (int o = 32; o > 0; o >>= 1) m = fmaxf(m, __shfl_xor(m, o));
    if ((t & 63) == 0) redM[t >> 6] = m;
    __syncthreads();
    m = fmaxf(redM[0], redM[1]);
    float e = expf(v - m);
    float s = e;
    #pragma unroll
    for (int o = 32; o > 0; o >>= 1) s += __shfl_xor(s, o);
    if ((t & 63) == 0) redS[t >> 6] = s;
    __syncthreads();
    s = redS[0] + redS[1];
    float w = e / s;
    if (t == c) w = 0.f;                  // zero diagonal AFTER softmax
    unsigned short hb = bfbits(w);
    whi[c * C_DIM + t] = hb;
    wlo[c * C_DIM + t] = bfbits(w - bits2f(hb));
}

// ---------- KP: elementwise hi/lo bf16 split of a f32 weight tensor ----------
__global__ __launch_bounds__(256) void kP_split(const float* __restrict__ src,
                                                unsigned short* __restrict__ hi,
                                                unsigned short* __restrict__ lo) {
    const int i = blockIdx.x * 256 + threadIdx.x;   // index in float4 units
    const float4 v = ((const float4*)src)[i];
    float f[4] = {v.x, v.y, v.z, v.w};
    unsigned short h[4], l[4];
    #pragma unroll
    for (int j = 0; j < 4; ++j) {
        h[j] = bfbits(f[j]);
        l[j] = bfbits(f[j] - bits2f(h[j]));
    }
    ((ushort4*)hi)[i] = make_ushort4(h[0], h[1], h[2], h[3]);
    ((ushort4*)lo)[i] = make_ushort4(l[0], l[1], l[2], l[3]);
}

// ---------- K1: value MLP + L2 norm, MFMA. Output V[r][n8][e][8n] bf16 ----------
// block = 64 rows x 8 columns, 8 waves (1 column each). D: m=r, n=f.
// W2 B-frags rotating-double-buffered (k2 pattern); 32KB LDS repack in 2 passes.
__global__ __launch_bounds__(512, 4) void k1_value(
        const float* __restrict__ samples, const float* __restrict__ W1,
        const float* __restrict__ b1, const unsigned short* __restrict__ W2hi,
        const unsigned short* __restrict__ W2lo, const float* __restrict__ b2,
        uint32_t* __restrict__ vbuf, int rowOff) {
    __shared__ char sOut[32 * 1024];       // [r32][f][c_local] bf16, XOR-swizzled
    const int t = threadIdx.x;
    const int rt = blockIdx.x, cg = blockIdx.y;
    const int r0 = rt * 64;
    const int cl = t >> 6;                 // wave = local column
    const int lane = t & 63;
    const int lm = lane & 15, lg = lane >> 4;
    const int c = cg * 8 + cl;

    // scatter sample loads issued first (deepest latency)
    float sv[4];
    #pragma unroll
    for (int mt = 0; mt < 4; ++mt)
        sv[mt] = samples[(size_t)(rowOff + r0 + mt * 16 + lm) * C_DIM + c];

    float b2r[4];
    #pragma unroll
    for (int nt = 0; nt < 4; ++nt) b2r[nt] = b2[(size_t)c * 64 + nt * 16 + lm];

    f32x4 acc[4][4];
    #pragma unroll
    for (int mt = 0; mt < 4; ++mt)
        #pragma unroll
        for (int nt = 0; nt < 4; ++nt)
            acc[mt][nt] = (f32x4){0.f, 0.f, 0.f, 0.f};

    #pragma unroll
    for (int ks = 0; ks < 2; ++ks) {
        const size_t wbase = ((size_t)c * 64) * 64 + ks * 32 + lg * 8;

        // rotating double-buffer of B-frag pairs (static names, rule #20)
        short8 bhA = *(const short8*)(W2hi + wbase + (size_t)(0 * 16 + lm) * 64);
        short8 blA = *(const short8*)(W2lo + wbase + (size_t)(0 * 16 + lm) * 64);
        short8 bhB = *(const short8*)(W2hi + wbase + (size_t)(1 * 16 + lm) * 64);
        short8 blB = *(const short8*)(W2lo + wbase + (size_t)(1 * 16 + lm) * 64);

        // W1/b1 slices for this ks (k-contiguous 8 elems)
        const float4 w1a = *(const float4*)(W1 + (size_t)c * 64 + ks * 32 + lg * 8);
        const float4 w1b = *(const float4*)(W1 + (size_t)c * 64 + ks * 32 + lg * 8 + 4);
        const float4 b1a = *(const float4*)(b1 + (size_t)c * 64 + ks * 32 + lg * 8);
        const float4 b1b = *(const float4*)(b1 + (size_t)c * 64 + ks * 32 + lg * 8 + 4);
        const float w1r[8] = {w1a.x, w1a.y, w1a.z, w1a.w, w1b.x, w1b.y, w1b.z, w1b.w};
        const float b1r[8] = {b1a.x, b1a.y, b1a.z, b1a.w, b1b.x, b1b.y, b1b.z, b1b.w};

        // A-frags (VALU work overlaps the in-flight B loads)
        short8 afr[4];
        #pragma unroll
        for (int mt = 0; mt < 4; ++mt) {
            Frag8 af;
            #pragma unroll
            for (int j = 0; j < 8; ++j)
                af.s[j] = (short)bfbits(fmaxf(fmaf(sv[mt], w1r[j], b1r[j]), 0.f));
            afr[mt] = af.v;
        }

#define K1_STEP(NT, BH, BL, PF_NT)                                                         \
        {                                                                                  \
            if (PF_NT >= 0) {                                                              \
                BH = *(const short8*)(W2hi + wbase + (size_t)((PF_NT) * 16 + lm) * 64);    \
                BL = *(const short8*)(W2lo + wbase + (size_t)((PF_NT) * 16 + lm) * 64);    \
            }                                                                              \
            _Pragma("unroll")                                                              \
            for (int mt = 0; mt < 4; ++mt)                                                 \
                acc[mt][NT] = __builtin_amdgcn_mfma_f32_16x16x32_bf16(afr[mt],             \
                    (PF_NT >= 0) ? bhPrev : BH, acc[mt][NT], 0, 0, 0);                     \
        }
        // explicit schedule: MFMA(cur) then prefetch(next) — written out longhand
        {
            // nt = 0 uses A-pair; prefetch nt=2 into A after use
            #pragma unroll
            for (int mt = 0; mt < 4; ++mt)
                acc[mt][0] = __builtin_amdgcn_mfma_f32_16x16x32_bf16(afr[mt], bhA, acc[mt][0], 0, 0, 0);
            #pragma unroll
            for (int mt = 0; mt < 4; ++mt)
                acc[mt][0] = __builtin_amdgcn_mfma_f32_16x16x32_bf16(afr[mt], blA, acc[mt][0], 0, 0, 0);
            bhA = *(const short8*)(W2hi + wbase + (size_t)(2 * 16 + lm) * 64);
            blA = *(const short8*)(W2lo + wbase + (size_t)(2 * 16 + lm) * 64);

            #pragma unroll
            for (int mt = 0; mt < 4; ++mt)
                acc[mt][1] = __builtin_amdgcn_mfma_f32_16x16x32_bf16(afr[mt], bhB, acc[mt][1], 0, 0, 0);
            #pragma unroll
            for (int mt = 0; mt < 4; ++mt)
                acc[mt][1] = __builtin_amdgcn_mfma_f32_16x16x32_bf16(afr[mt], blB, acc[mt][1], 0, 0, 0);
            bhB = *(const short8*)(W2hi + wbase + (size_t)(3 * 16 + lm) * 64);
            blB = *(const short8*)(W2lo + wbase + (size_t)(3 * 16 + lm) * 64);

            #pragma unroll
            for (int mt = 0; mt < 4; ++mt)
                acc[mt][2] = __builtin_amdgcn_mfma_f32_16x16x32_bf16(afr[mt], bhA, acc[mt][2], 0, 0, 0);
            #pragma unroll
            for (int mt = 0; mt < 4; ++mt)
                acc[mt][2] = __builtin_amdgcn_mfma_f32_16x16x32_bf16(afr[mt], blA, acc[mt][2], 0, 0, 0);

            #pragma unroll
            for (int mt = 0; mt < 4; ++mt)
                acc[mt][3] = __builtin_amdgcn_mfma_f32_16x16x32_bf16(afr[mt], bhB, acc[mt][3], 0, 0, 0);
            #pragma unroll
            for (int mt = 0; mt < 4; ++mt)
                acc[mt][3] = __builtin_amdgcn_mfma_f32_16x16x32_bf16(afr[mt], blB, acc[mt][3], 0, 0, 0);
        }
#undef K1_STEP
    }

    // add b2, sum of squares over f (lane-local over nt, butterfly over lm lanes)
    float rsc[4][4];
    #pragma unroll
    for (int mt = 0; mt < 4; ++mt)
        #pragma unroll
        for (int i = 0; i < 4; ++i) {
            float s2 = 0.f;
            #pragma unroll
            for (int nt = 0; nt < 4; ++nt) {
                float vv = acc[mt][nt][i] + b2r[nt];
                acc[mt][nt][i] = vv;
                s2 = fmaf(vv, vv, s2);
            }
            s2 += __shfl_xor(s2, 1); s2 += __shfl_xor(s2, 2);
            s2 += __shfl_xor(s2, 4); s2 += __shfl_xor(s2, 8);
            rsc[mt][i] = 1.f / fmaxf(sqrtf(s2), 1e-12f);
        }

    // two 32-row passes: repack into 32KB LDS, then coalesced writeout
    #pragma unroll
    for (int p = 0; p < 2; ++p) {
        if (p) __syncthreads();            // protect previous readout
        #pragma unroll
        for (int mh = 0; mh < 2; ++mh) {
            const int mt = p * 2 + mh;
            #pragma unroll
            for (int i = 0; i < 4; ++i) {
                const int rl = mh * 16 + lg * 4 + i;      // local row 0..31
                const uint32_t rowbase = (uint32_t)rl * 1024u;
                const uint32_t swz = (uint32_t)(rl & 7) << 4;
                #pragma unroll
                for (int nt = 0; nt < 4; ++nt) {
                    const int f = nt * 16 + lm;
                    const uint32_t bo = (rowbase + (uint32_t)f * 16u + (uint32_t)cl * 2u) ^ swz;
                    *(unsigned short*)(sOut + bo) = bfbits(acc[mt][nt][i] * rsc[mt][i]);
                }
            }
        }
        __syncthreads();
        #pragma unroll
        for (int it = 0; it < 4; ++it) {
            const int unit = t + it * 512;
            const int rl = unit >> 6, f = unit & 63;
            const uint32_t lb = ((uint32_t)rl * 1024u + (uint32_t)f * 16u) ^ ((uint32_t)(rl & 7) << 4);
            const uint4 val = *(const uint4*)(sOut + lb);
            ((uint4*)vbuf)[((size_t)(r0 + p * 32 + rl) * 16 + cg) * 64 + f] = val;
        }
    }
}

// ---------- K2: ctx[r][c][e] = sum_n w[c,n] V[r,n,e]  (separate output buffer) ----------
// block = 256 thr, 4 waves = (rg 0..1, ch 0..1); 4 rows/block, 2 rows/wave.
// w hi+lo staged once in LDS (XOR-swizzled); V A-frags streamed direct from global.
__global__ __launch_bounds__(256) void k2_ctx(
        const unsigned short* __restrict__ whi, const unsigned short* __restrict__ wlo,
        const uint32_t* __restrict__ vbuf, uint32_t* __restrict__ cbuf) {
    __shared__ char sW[65536];   // [hi 32K | lo 32K], 256 B per c-row, byte^=((c&7)<<4)
    const int t = threadIdx.x;
    const int lane = t & 63, wv = t >> 6;
    const int lm = lane & 15, lg = lane >> 4;

    #pragma unroll
    for (int i = 0; i < 8; ++i) {
        const int idx = t + i * 256;                       // 16B-unit index within 32KB
        const int c = idx >> 4;
        const uint32_t bo = (((uint32_t)idx * 16u) ^ (((uint32_t)c & 7u) << 4));
        *(uint4*)(sW + bo)         = ((const uint4*)whi)[idx];
        *(uint4*)(sW + 32768 + bo) = ((const uint4*)wlo)[idx];
    }
    __syncthreads();

    const int rg = wv >> 1, ch = wv & 1;
    const int c0 = ch * 64;
    const size_t rbase = (size_t)blockIdx.x * 4 + (size_t)rg * 2;

    #pragma unroll 1
    for (int rr = 0; rr < 2; ++rr) {
        const size_t r = rbase + rr;
        const char* vrow = (const char*)vbuf + (r << 14);

        short8 aA[4], aB[4];   // ks double-buffer (static names, rule #20)
        #pragma unroll
        for (int et = 0; et < 4; ++et)
            aA[et] = *(const short8*)(vrow + (0 * 4 + lg) * 1024 + (et * 16 + lm) * 16);

        f32x4 acc[4][4];       // [et][nt]
        #pragma unroll
        for (int et = 0; et < 4; ++et)
            #pragma unroll
            for (int nt = 0; nt < 4; ++nt)
                acc[et][nt] = (f32x4){0.f, 0.f, 0.f, 0.f};

#define K2_STEP(KS, ACUR, ANXT, PREFETCH)                                                  \
        {                                                                                  \
            if (PREFETCH) {                                                                \
                _Pragma("unroll")                                                          \
                for (int et = 0; et < 4; ++et)                                             \
                    ANXT[et] = *(const short8*)(vrow + ((KS + 1) * 4 + lg) * 1024 +        \
                                                (et * 16 + lm) * 16);                      \
            }                                                                              \
            _Pragma("unroll")                                                              \
            for (int nt = 0; nt < 4; ++nt) {                                               \
                const int cc = c0 + nt * 16 + lm;                                          \
                const uint32_t wb = (((uint32_t)cc * 256u +                                \
                                      (uint32_t)((KS) * 32 + lg * 8) * 2u) ^               \
                                     (((uint32_t)cc & 7u) << 4));                          \
                const short8 bh = *(const short8*)(sW + wb);                               \
                const short8 bl = *(const short8*)(sW + 32768 + wb);                       \
                _Pragma("unroll")                                                          \
                for (int et = 0; et < 4; ++et) {                                           \
                    acc[et][nt] = __builtin_amdgcn_mfma_f32_16x16x32_bf16(ACUR[et], bh,    \
                                                                 acc[et][nt], 0, 0, 0);    \
                    acc[et][nt] = __builtin_amdgcn_mfma_f32_16x16x32_bf16(ACUR[et], bl,    \
                                                                 acc[et][nt], 0, 0, 0);    \
                }                                                                          \
            }                                                                              \
        }
        K2_STEP(0, aA, aB, 1)
        K2_STEP(1, aB, aA, 1)
        K2_STEP(2, aA, aB, 1)
        K2_STEP(3, aB, aA, 0)
#undef K2_STEP

        // store ctx[r][c][e] bf16, 8 B per (et,nt) per lane
        char* crow = (char*)cbuf + (r << 14);
        #pragma unroll
        for (int et = 0; et < 4; ++et)
            #pragma unroll
            for (int nt = 0; nt < 4; ++nt) {
                const uint32_t u0 = (uint32_t)bfbits(acc[et][nt][0]) | ((uint32_t)bfbits(acc[et][nt][1]) << 16);
                const uint32_t u1 = (uint32_t)bfbits(acc[et][nt][2]) | ((uint32_t)bfbits(acc[et][nt][3]) << 16);
                *(uint2*)(crow + (size_t)(c0 + nt * 16 + lm) * 128 + (size_t)(et * 16 + lg * 4) * 2) =
                    make_uint2(u0, u1);
            }
    }
}

// ---------- K3: out = P2 . relu(P1 @ ctx + pb1) + pb2, MFMA, LDS-staged ----------
// block = 64 rows x 8 columns, 8 waves (1 column each). M=r (4 tiles), N=f, K=e.
__global__ __launch_bounds__(512) void k3_out(
        const uint32_t* __restrict__ cbuf, const unsigned short* __restrict__ P1hi,
        const unsigned short* __restrict__ P1lo, const float* __restrict__ pb1,
        const float* __restrict__ P2, const float* __restrict__ pb2,
        float* __restrict__ out, int rowOff) {
    __shared__ char sC[64 * 1024];          // [r][c_local][e] bf16, 64KB, XOR-swizzled
    const int t = threadIdx.x;
    const int cg = blockIdx.x;              // 16 groups of 8 columns
    const int r0 = blockIdx.y * 64;         // chunk-local
    const int lane = t & 63, wv = t >> 6;
    const int lm = lane & 15, lg = lane >> 4;
    const int cl = wv;
    const int c = cg * 8 + cl;

    // stage ctx[r0..r0+63][cg*8..+8][all e] coalesced: 1KB contiguous per row
    {
        const int rr = t >> 6;              // 8 rows per pass
        const int inner = t & 63;           // 16B chunk within the 1KB c-window
        #pragma unroll
        for (int p = 0; p < 8; ++p) {
            const int r = p * 8 + rr;
            const uint4 val = *(const uint4*)((const char*)cbuf +
                (size_t)(r0 + r) * 16384 + (size_t)cg * 1024 + (size_t)inner * 16);
            const uint32_t bo = ((uint32_t)r * 1024u + (uint32_t)inner * 16u) ^ ((uint32_t)(r & 7) << 4);
            *(uint4*)(sC + bo) = val;
        }
    }
    __syncthreads();

    float pb1r[4], p2r[4];
    #pragma unroll
    for (int nt = 0; nt < 4; ++nt) {
        pb1r[nt] = pb1[(size_t)c * 64 + nt * 16 + lm];
        p2r[nt]  = P2[(size_t)c * 64 + nt * 16 + lm];
    }
    const float pb2c = pb2[c];

    f32x4 acc[4][4];                        // [mt][nt]
    #pragma unroll
    for (int mt = 0; mt < 4; ++mt)
        #pragma unroll
        for (int nt = 0; nt < 4; ++nt)
            acc[mt][nt] = (f32x4){0.f, 0.f, 0.f, 0.f};

    #pragma unroll
    for (int ks = 0; ks < 2; ++ks) {
        short8 a[4];
        #pragma unroll
        for (int mt = 0; mt < 4; ++mt) {
            const int rl = mt * 16 + lm;
            const uint32_t bo = ((uint32_t)rl * 1024u + (uint32_t)cl * 128u +
                                 (uint32_t)ks * 64u + (uint32_t)lg * 16u) ^ ((uint32_t)(rl & 7) << 4);
            a[mt] = *(const short8*)(sC + bo);
        }
        #pragma unroll
        for (int nt = 0; nt < 4; ++nt) {
            const size_t wb = ((size_t)c * 64 + nt * 16 + lm) * 64 + ks * 32 + lg * 8;
            const short8 bh = *(const short8*)(P1hi + wb);
            const short8 bl = *(const short8*)(P1lo + wb);
            #pragma unroll
            for (int mt = 0; mt < 4; ++mt) {
                acc[mt][nt] = __builtin_amdgcn_mfma_f32_16x16x32_bf16(a[mt], bh, acc[mt][nt], 0, 0, 0);
                acc[mt][nt] = __builtin_amdgcn_mfma_f32_16x16x32_bf16(a[mt], bl, acc[mt][nt], 0, 0, 0);
            }
        }
    }

    // epilogue: relu, dot with P2 over f (lane-local nt + butterfly over lm), store
    #pragma unroll
    for (int mt = 0; mt < 4; ++mt)
        #pragma unroll
        for (int i = 0; i < 4; ++i) {
            float p = 0.f;
            #pragma unroll
            for (int nt = 0; nt < 4; ++nt)
                p = fmaf(fmaxf(acc[mt][nt][i] + pb1r[nt], 0.f), p2r[nt], p);
            p += __shfl_xor(p, 1); p += __shfl_xor(p, 2);
            p += __shfl_xor(p, 4); p += __shfl_xor(p, 8);
            if (lm == 0)
                out[(size_t)(rowOff + r0 + mt * 16 + lg * 4 + i) * C_DIM + c] = p + pb2c;
        }
}

// ---------- host ----------
extern "C" void kernel_launch(void* const* d_in, const int* in_sizes, int n_in,
                              void* d_out, int out_size, void* d_ws, size_t ws_size,
                              hipStream_t stream) {
    const float* samples = (const float*)d_in[0];
    const float* W1  = (const float*)d_in[1];
    const float* b1  = (const float*)d_in[2];
    const float* W2  = (const float*)d_in[3];
    const float* b2  = (const float*)d_in[4];
    const float* q   = (const float*)d_in[5];
    const float* P1  = (const float*)d_in[6];
    const float* pb1 = (const float*)d_in[7];
    const float* P2  = (const float*)d_in[8];
    const float* pb2 = (const float*)d_in[9];
    float* out = (float*)d_out;

    char* ws = (char*)d_ws;
    unsigned short* whi  = (unsigned short*)ws;                       // 32KB
    unsigned short* wlo  = (unsigned short*)(ws + 32768);             // 32KB
    unsigned short* W2hi = (unsigned short*)(ws + 65536);             // 1MB
    unsigned short* W2lo = (unsigned short*)(ws + 65536 + 1048576);   // 1MB
    unsigned short* P1hi = (unsigned short*)(ws + 65536 + 2097152);   // 1MB
    unsigned short* P1lo = (unsigned short*)(ws + 65536 + 3145728);   // 1MB
    const size_t head = 65536 + 4194304;

    // two regions: V and ctx, each maxRows*16KB
    size_t avail = (ws_size > head) ? ws_size - head : 0;
    long maxRows = (long)(avail / ((size_t)2 * C_DIM * E_DIM * 2));
    maxRows = (maxRows / 256) * 256;
    if (maxRows > B_DIM) maxRows = B_DIM;
    if (maxRows < 256) maxRows = 256;

    uint32_t* vbuf = (uint32_t*)(ws + head);
    uint32_t* cbuf = (uint32_t*)(ws + head + (size_t)maxRows * 16384);

    k0_softmax<<<dim3(C_DIM), dim3(C_DIM), 0, stream>>>(q, whi, wlo);
    kP_split<<<dim3(512), 256, 0, stream>>>(W2, W2hi, W2lo);   // 524288 floats / 4 / 256
    kP_split<<<dim3(512), 256, 0, stream>>>(P1, P1hi, P1lo);

    for (int off = 0; off < B_DIM; off += (int)maxRows) {
        const int rows = (int)(((long)(B_DIM - off) < maxRows) ? (long)(B_DIM - off) : maxRows);
        k1_value<<<dim3(rows / 64, 16), 512, 0, stream>>>(samples, W1, b1, W2hi, W2lo, b2, vbuf, off);
        k2_ctx<<<dim3(rows / 4), 256, 0, stream>>>(whi, wlo, vbuf, cbuf);
        k3_out<<<dim3(16, rows / 64), 512, 0, stream>>>(cbuf, P1hi, P1lo, pb1, P2, pb2, out, off);
    }
}

// Round 6
// 241.953 us; speedup vs baseline: 3.1160x; 1.0111x over previous
//
#include <hip/hip_runtime.h>
#include <hip/hip_bf16.h>
#include <cstdint>

#define C_DIM 128
#define E_DIM 64
#define B_DIM 8192

typedef __attribute__((ext_vector_type(8))) short short8;
typedef __attribute__((ext_vector_type(4))) float f32x4;

union Frag8 { short8 v; short s[8]; uint32_t u[4]; };

__device__ __forceinline__ unsigned short bfbits(float x) {
    union { __hip_bfloat16 h; unsigned short u; } cv;
    cv.h = __float2bfloat16(x);
    return cv.u;
}
__device__ __forceinline__ float bits2f(unsigned short b) {
    return __uint_as_float(((uint32_t)b) << 16);
}

// ---------- K0: w = softmax(q,axis=1), zero diag, split hi/lo bf16, layout [c][n] ----------
__global__ __launch_bounds__(128) void k0_softmax(const float* __restrict__ q,
                                                  unsigned short* __restrict__ whi,
                                                  unsigned short* __restrict__ wlo) {
    const int c = blockIdx.x;
    const int t = threadIdx.x;            // n
    __shared__ float redM[2], redS[2];
    float v = q[c * C_DIM + t];
    float m = v;
    #pragma unroll
    for (int o = 32; o > 0; o >>= 1) m = fmaxf(m, __shfl_xor(m, o));
    if ((t & 63) == 0) redM[t >> 6] = m;
    __syncthreads();
    m = fmaxf(redM[0], redM[1]);
    float e = expf(v - m);
    float s = e;
    #pragma unroll
    for (int o = 32; o > 0; o >>= 1) s += __shfl_xor(s, o);
    if ((t & 63) == 0) redS[t >> 6] = s;
    __syncthreads();
    s = redS[0] + redS[1];
    float w = e / s;
    if (t == c) w = 0.f;                  // zero diagonal AFTER softmax
    unsigned short hb = bfbits(w);
    whi[c * C_DIM + t] = hb;
    wlo[c * C_DIM + t] = bfbits(w - bits2f(hb));
}

// ---------- KP: elementwise hi/lo bf16 split of a f32 weight tensor ----------
__global__ __launch_bounds__(256) void kP_split(const float* __restrict__ src,
                                                unsigned short* __restrict__ hi,
                                                unsigned short* __restrict__ lo) {
    const int i = blockIdx.x * 256 + threadIdx.x;   // index in float4 units
    const float4 v = ((const float4*)src)[i];
    float f[4] = {v.x, v.y, v.z, v.w};
    unsigned short h[4], l[4];
    #pragma unroll
    for (int j = 0; j < 4; ++j) {
        h[j] = bfbits(f[j]);
        l[j] = bfbits(f[j] - bits2f(h[j]));
    }
    ((ushort4*)hi)[i] = make_ushort4(h[0], h[1], h[2], h[3]);
    ((ushort4*)lo)[i] = make_ushort4(l[0], l[1], l[2], l[3]);
}

// ---------- K1: value MLP + L2 norm, MFMA. Output V[r][n8][e][8n] bf16 ----------
// block = 64 rows x 8 columns, 8 waves (1 column each). D: m=r, n=f.
__global__ __launch_bounds__(512, 4) void k1_value(
        const float* __restrict__ samples, const float* __restrict__ W1,
        const float* __restrict__ b1, const unsigned short* __restrict__ W2hi,
        const unsigned short* __restrict__ W2lo, const float* __restrict__ b2,
        uint32_t* __restrict__ vbuf, int rowOff) {
    __shared__ char sOut[32 * 1024];       // [r32][f][c_local] bf16, XOR-swizzled
    const int t = threadIdx.x;
    const int rt = blockIdx.x, cg = blockIdx.y;
    const int r0 = rt * 64;
    const int cl = t >> 6;                 // wave = local column
    const int lane = t & 63;
    const int lm = lane & 15, lg = lane >> 4;
    const int c = cg * 8 + cl;

    // scatter sample loads issued first (deepest latency)
    float sv[4];
    #pragma unroll
    for (int mt = 0; mt < 4; ++mt)
        sv[mt] = samples[(size_t)(rowOff + r0 + mt * 16 + lm) * C_DIM + c];

    float b2r[4];
    #pragma unroll
    for (int nt = 0; nt < 4; ++nt) b2r[nt] = b2[(size_t)c * 64 + nt * 16 + lm];

    f32x4 acc[4][4];
    #pragma unroll
    for (int mt = 0; mt < 4; ++mt)
        #pragma unroll
        for (int nt = 0; nt < 4; ++nt)
            acc[mt][nt] = (f32x4){0.f, 0.f, 0.f, 0.f};

    #pragma unroll
    for (int ks = 0; ks < 2; ++ks) {
        const size_t wbase = ((size_t)c * 64) * 64 + ks * 32 + lg * 8;

        // rotating double-buffer of B-frag pairs (static names, rule #20)
        short8 bhA = *(const short8*)(W2hi + wbase + (size_t)(0 * 16 + lm) * 64);
        short8 blA = *(const short8*)(W2lo + wbase + (size_t)(0 * 16 + lm) * 64);
        short8 bhB = *(const short8*)(W2hi + wbase + (size_t)(1 * 16 + lm) * 64);
        short8 blB = *(const short8*)(W2lo + wbase + (size_t)(1 * 16 + lm) * 64);

        // W1/b1 slices for this ks (k-contiguous 8 elems)
        const float4 w1a = *(const float4*)(W1 + (size_t)c * 64 + ks * 32 + lg * 8);
        const float4 w1b = *(const float4*)(W1 + (size_t)c * 64 + ks * 32 + lg * 8 + 4);
        const float4 b1a = *(const float4*)(b1 + (size_t)c * 64 + ks * 32 + lg * 8);
        const float4 b1b = *(const float4*)(b1 + (size_t)c * 64 + ks * 32 + lg * 8 + 4);
        const float w1r[8] = {w1a.x, w1a.y, w1a.z, w1a.w, w1b.x, w1b.y, w1b.z, w1b.w};
        const float b1r[8] = {b1a.x, b1a.y, b1a.z, b1a.w, b1b.x, b1b.y, b1b.z, b1b.w};

        // A-frags (VALU work overlaps the in-flight B loads)
        short8 afr[4];
        #pragma unroll
        for (int mt = 0; mt < 4; ++mt) {
            Frag8 af;
            #pragma unroll
            for (int j = 0; j < 8; ++j)
                af.s[j] = (short)bfbits(fmaxf(fmaf(sv[mt], w1r[j], b1r[j]), 0.f));
            afr[mt] = af.v;
        }

        // explicit schedule: MFMA(cur) then prefetch(next)
        {
            #pragma unroll
            for (int mt = 0; mt < 4; ++mt)
                acc[mt][0] = __builtin_amdgcn_mfma_f32_16x16x32_bf16(afr[mt], bhA, acc[mt][0], 0, 0, 0);
            #pragma unroll
            for (int mt = 0; mt < 4; ++mt)
                acc[mt][0] = __builtin_amdgcn_mfma_f32_16x16x32_bf16(afr[mt], blA, acc[mt][0], 0, 0, 0);
            bhA = *(const short8*)(W2hi + wbase + (size_t)(2 * 16 + lm) * 64);
            blA = *(const short8*)(W2lo + wbase + (size_t)(2 * 16 + lm) * 64);

            #pragma unroll
            for (int mt = 0; mt < 4; ++mt)
                acc[mt][1] = __builtin_amdgcn_mfma_f32_16x16x32_bf16(afr[mt], bhB, acc[mt][1], 0, 0, 0);
            #pragma unroll
            for (int mt = 0; mt < 4; ++mt)
                acc[mt][1] = __builtin_amdgcn_mfma_f32_16x16x32_bf16(afr[mt], blB, acc[mt][1], 0, 0, 0);
            bhB = *(const short8*)(W2hi + wbase + (size_t)(3 * 16 + lm) * 64);
            blB = *(const short8*)(W2lo + wbase + (size_t)(3 * 16 + lm) * 64);

            #pragma unroll
            for (int mt = 0; mt < 4; ++mt)
                acc[mt][2] = __builtin_amdgcn_mfma_f32_16x16x32_bf16(afr[mt], bhA, acc[mt][2], 0, 0, 0);
            #pragma unroll
            for (int mt = 0; mt < 4; ++mt)
                acc[mt][2] = __builtin_amdgcn_mfma_f32_16x16x32_bf16(afr[mt], blA, acc[mt][2], 0, 0, 0);

            #pragma unroll
            for (int mt = 0; mt < 4; ++mt)
                acc[mt][3] = __builtin_amdgcn_mfma_f32_16x16x32_bf16(afr[mt], bhB, acc[mt][3], 0, 0, 0);
            #pragma unroll
            for (int mt = 0; mt < 4; ++mt)
                acc[mt][3] = __builtin_amdgcn_mfma_f32_16x16x32_bf16(afr[mt], blB, acc[mt][3], 0, 0, 0);
        }
    }

    // add b2, sum of squares over f (lane-local over nt, butterfly over lm lanes)
    float rsc[4][4];
    #pragma unroll
    for (int mt = 0; mt < 4; ++mt)
        #pragma unroll
        for (int i = 0; i < 4; ++i) {
            float s2 = 0.f;
            #pragma unroll
            for (int nt = 0; nt < 4; ++nt) {
                float vv = acc[mt][nt][i] + b2r[nt];
                acc[mt][nt][i] = vv;
                s2 = fmaf(vv, vv, s2);
            }
            s2 += __shfl_xor(s2, 1); s2 += __shfl_xor(s2, 2);
            s2 += __shfl_xor(s2, 4); s2 += __shfl_xor(s2, 8);
            rsc[mt][i] = 1.f / fmaxf(sqrtf(s2), 1e-12f);
        }

    // two 32-row passes: repack into 32KB LDS, then coalesced writeout
    #pragma unroll
    for (int p = 0; p < 2; ++p) {
        if (p) __syncthreads();            // protect previous readout
        #pragma unroll
        for (int mh = 0; mh < 2; ++mh) {
            const int mt = p * 2 + mh;
            #pragma unroll
            for (int i = 0; i < 4; ++i) {
                const int rl = mh * 16 + lg * 4 + i;      // local row 0..31
                const uint32_t rowbase = (uint32_t)rl * 1024u;
                const uint32_t swz = (uint32_t)(rl & 7) << 4;
                #pragma unroll
                for (int nt = 0; nt < 4; ++nt) {
                    const int f = nt * 16 + lm;
                    const uint32_t bo = (rowbase + (uint32_t)f * 16u + (uint32_t)cl * 2u) ^ swz;
                    *(unsigned short*)(sOut + bo) = bfbits(acc[mt][nt][i] * rsc[mt][i]);
                }
            }
        }
        __syncthreads();
        #pragma unroll
        for (int it = 0; it < 4; ++it) {
            const int unit = t + it * 512;
            const int rl = unit >> 6, f = unit & 63;
            const uint32_t lb = ((uint32_t)rl * 1024u + (uint32_t)f * 16u) ^ ((uint32_t)(rl & 7) << 4);
            const uint4 val = *(const uint4*)(sOut + lb);
            ((uint4*)vbuf)[((size_t)(r0 + p * 32 + rl) * 16 + cg) * 64 + f] = val;
        }
    }
}

// ---------- K23: fused ctx + projection.  out[r][c] = P2[c].relu(P1[c]@ctx + pb1[c]) + pb2[c]
// block = 512 thr (8 waves), 32 rows; 4 column-groups of 32.
// phase A (per g): wave computes ctx[4 rows][32 c][64 e] -> LDS (bf16, XOR-swizzled)
// phase B (per g): wave projects 4 columns, M = 32 rows (2 MFMA tiles), out -> global
__global__ __launch_bounds__(512) void k23_fused(
        const unsigned short* __restrict__ whi, const unsigned short* __restrict__ wlo,
        const uint32_t* __restrict__ vbuf,
        const unsigned short* __restrict__ P1hi, const unsigned short* __restrict__ P1lo,
        const float* __restrict__ pb1, const float* __restrict__ P2,
        const float* __restrict__ pb2, float* __restrict__ out, int rowOff) {
    __shared__ char sCtx[32 * 32 * 64 * 2];   // 128 KB: [32r][32c][64e] bf16, ^((r^c)&7)<<4
    const int t = threadIdx.x;
    const int lane = t & 63, wv = t >> 6;
    const int lm = lane & 15, lg = lane >> 4;
    const int R0 = blockIdx.x * 32;

    #pragma unroll 1
    for (int g = 0; g < 4; ++g) {
        // ---------------- phase A: ctx into LDS ----------------
        // hoist w B-frags for this g (hi & lo), straight from L2
        short8 wh[2][4], wl[2][4];
        #pragma unroll
        for (int mt = 0; mt < 2; ++mt)
            #pragma unroll
            for (int ks = 0; ks < 4; ++ks) {
                const size_t wb = (size_t)(g * 32 + mt * 16 + lm) * C_DIM + ks * 32 + lg * 8;
                wh[mt][ks] = *(const short8*)(whi + wb);
                wl[mt][ks] = *(const short8*)(wlo + wb);
            }

        #pragma unroll 1
        for (int rr = 0; rr < 4; ++rr) {
            const int rloc = wv * 4 + rr;
            const char* vrow = (const char*)vbuf + ((size_t)(R0 + rloc) << 14);

            f32x4 acc[4][2];    // [et][mt]
            #pragma unroll
            for (int et = 0; et < 4; ++et)
                #pragma unroll
                for (int mt = 0; mt < 2; ++mt)
                    acc[et][mt] = (f32x4){0.f, 0.f, 0.f, 0.f};

            short8 vA0, vA1, vA2, vA3, vB0, vB1, vB2, vB3;   // ks double-buffer
            vA0 = *(const short8*)(vrow + (0 * 4 + lg) * 1024 + (0 * 16 + lm) * 16);
            vA1 = *(const short8*)(vrow + (0 * 4 + lg) * 1024 + (1 * 16 + lm) * 16);
            vA2 = *(const short8*)(vrow + (0 * 4 + lg) * 1024 + (2 * 16 + lm) * 16);
            vA3 = *(const short8*)(vrow + (0 * 4 + lg) * 1024 + (3 * 16 + lm) * 16);

#define K23A_STEP(KS, V0, V1, V2, V3, N0, N1, N2, N3, PF)                                   \
            {                                                                               \
                if (PF) {                                                                   \
                    N0 = *(const short8*)(vrow + ((KS + 1) * 4 + lg) * 1024 + (0 * 16 + lm) * 16); \
                    N1 = *(const short8*)(vrow + ((KS + 1) * 4 + lg) * 1024 + (1 * 16 + lm) * 16); \
                    N2 = *(const short8*)(vrow + ((KS + 1) * 4 + lg) * 1024 + (2 * 16 + lm) * 16); \
                    N3 = *(const short8*)(vrow + ((KS + 1) * 4 + lg) * 1024 + (3 * 16 + lm) * 16); \
                }                                                                           \
                _Pragma("unroll")                                                           \
                for (int mt = 0; mt < 2; ++mt) {                                            \
                    acc[0][mt] = __builtin_amdgcn_mfma_f32_16x16x32_bf16(V0, wh[mt][KS], acc[0][mt], 0, 0, 0); \
                    acc[0][mt] = __builtin_amdgcn_mfma_f32_16x16x32_bf16(V0, wl[mt][KS], acc[0][mt], 0, 0, 0); \
                    acc[1][mt] = __builtin_amdgcn_mfma_f32_16x16x32_bf16(V1, wh[mt][KS], acc[1][mt], 0, 0, 0); \
                    acc[1][mt] = __builtin_amdgcn_mfma_f32_16x16x32_bf16(V1, wl[mt][KS], acc[1][mt], 0, 0, 0); \
                    acc[2][mt] = __builtin_amdgcn_mfma_f32_16x16x32_bf16(V2, wh[mt][KS], acc[2][mt], 0, 0, 0); \
                    acc[2][mt] = __builtin_amdgcn_mfma_f32_16x16x32_bf16(V2, wl[mt][KS], acc[2][mt], 0, 0, 0); \
                    acc[3][mt] = __builtin_amdgcn_mfma_f32_16x16x32_bf16(V3, wh[mt][KS], acc[3][mt], 0, 0, 0); \
                    acc[3][mt] = __builtin_amdgcn_mfma_f32_16x16x32_bf16(V3, wl[mt][KS], acc[3][mt], 0, 0, 0); \
                }                                                                           \
            }
            K23A_STEP(0, vA0, vA1, vA2, vA3, vB0, vB1, vB2, vB3, 1)
            K23A_STEP(1, vB0, vB1, vB2, vB3, vA0, vA1, vA2, vA3, 1)
            K23A_STEP(2, vA0, vA1, vA2, vA3, vB0, vB1, vB2, vB3, 1)
            K23A_STEP(3, vB0, vB1, vB2, vB3, vA0, vA1, vA2, vA3, 0)
#undef K23A_STEP

            // write ctx[rloc][c][e] into LDS (8 B per tile per lane)
            #pragma unroll
            for (int et = 0; et < 4; ++et)
                #pragma unroll
                for (int mt = 0; mt < 2; ++mt) {
                    const int cloc = mt * 16 + lm;
                    const uint32_t u0 = (uint32_t)bfbits(acc[et][mt][0]) | ((uint32_t)bfbits(acc[et][mt][1]) << 16);
                    const uint32_t u1 = (uint32_t)bfbits(acc[et][mt][2]) | ((uint32_t)bfbits(acc[et][mt][3]) << 16);
                    uint32_t bo = (uint32_t)rloc * 4096u + (uint32_t)cloc * 128u +
                                  (uint32_t)(et * 32 + lg * 8);
                    bo ^= (uint32_t)((rloc ^ cloc) & 7) << 4;
                    *(uint2*)(sCtx + bo) = make_uint2(u0, u1);
                }
        }
        __syncthreads();

        // ---------------- phase B: projection for this wave's 4 columns ----------------
        #pragma unroll 1
        for (int cc = 0; cc < 4; ++cc) {
            const int cloc = wv * 4 + cc;          // 0..31 within group
            const int c = g * 32 + cloc;

            float pb1r[4], p2r[4];
            #pragma unroll
            for (int nt = 0; nt < 4; ++nt) {
                pb1r[nt] = pb1[(size_t)c * 64 + nt * 16 + lm];
                p2r[nt]  = P2[(size_t)c * 64 + nt * 16 + lm];
            }
            const float pb2c = pb2[c];

            f32x4 acc2[2][4];                      // [mt2][nt]
            #pragma unroll
            for (int mt2 = 0; mt2 < 2; ++mt2)
                #pragma unroll
                for (int nt = 0; nt < 4; ++nt)
                    acc2[mt2][nt] = (f32x4){0.f, 0.f, 0.f, 0.f};

            #pragma unroll
            for (int ks = 0; ks < 2; ++ks) {
                short8 a0, a1;
                {
                    const int rl0 = 0 * 16 + lm;
                    uint32_t bo = (uint32_t)rl0 * 4096u + (uint32_t)cloc * 128u +
                                  (uint32_t)(ks * 64 + lg * 16);
                    bo ^= (uint32_t)((rl0 ^ cloc) & 7) << 4;
                    a0 = *(const short8*)(sCtx + bo);
                }
                {
                    const int rl1 = 1 * 16 + lm;
                    uint32_t bo = (uint32_t)rl1 * 4096u + (uint32_t)cloc * 128u +
                                  (uint32_t)(ks * 64 + lg * 16);
                    bo ^= (uint32_t)((rl1 ^ cloc) & 7) << 4;
                    a1 = *(const short8*)(sCtx + bo);
                }
                #pragma unroll
                for (int nt = 0; nt < 4; ++nt) {
                    const size_t wb = ((size_t)c * 64 + nt * 16 + lm) * 64 + ks * 32 + lg * 8;
                    const short8 bh = *(const short8*)(P1hi + wb);
                    const short8 bl = *(const short8*)(P1lo + wb);
                    acc2[0][nt] = __builtin_amdgcn_mfma_f32_16x16x32_bf16(a0, bh, acc2[0][nt], 0, 0, 0);
                    acc2[0][nt] = __builtin_amdgcn_mfma_f32_16x16x32_bf16(a0, bl, acc2[0][nt], 0, 0, 0);
                    acc2[1][nt] = __builtin_amdgcn_mfma_f32_16x16x32_bf16(a1, bh, acc2[1][nt], 0, 0, 0);
                    acc2[1][nt] = __builtin_amdgcn_mfma_f32_16x16x32_bf16(a1, bl, acc2[1][nt], 0, 0, 0);
                }
            }

            // epilogue: relu, dot with P2 over f, butterfly over lm, store
            #pragma unroll
            for (int mt2 = 0; mt2 < 2; ++mt2)
                #pragma unroll
                for (int i = 0; i < 4; ++i) {
                    float p = 0.f;
                    #pragma unroll
                    for (int nt = 0; nt < 4; ++nt)
                        p = fmaf(fmaxf(acc2[mt2][nt][i] + pb1r[nt], 0.f), p2r[nt], p);
                    p += __shfl_xor(p, 1); p += __shfl_xor(p, 2);
                    p += __shfl_xor(p, 4); p += __shfl_xor(p, 8);
                    if (lm == 0)
                        out[(size_t)(rowOff + R0 + mt2 * 16 + lg * 4 + i) * C_DIM + c] = p + pb2c;
                }
        }
        __syncthreads();
    }
}

// ---------- host ----------
extern "C" void kernel_launch(void* const* d_in, const int* in_sizes, int n_in,
                              void* d_out, int out_size, void* d_ws, size_t ws_size,
                              hipStream_t stream) {
    const float* samples = (const float*)d_in[0];
    const float* W1  = (const float*)d_in[1];
    const float* b1  = (const float*)d_in[2];
    const float* W2  = (const float*)d_in[3];
    const float* b2  = (const float*)d_in[4];
    const float* q   = (const float*)d_in[5];
    const float* P1  = (const float*)d_in[6];
    const float* pb1 = (const float*)d_in[7];
    const float* P2  = (const float*)d_in[8];
    const float* pb2 = (const float*)d_in[9];
    float* out = (float*)d_out;

    char* ws = (char*)d_ws;
    unsigned short* whi  = (unsigned short*)ws;                       // 32KB
    unsigned short* wlo  = (unsigned short*)(ws + 32768);             // 32KB
    unsigned short* W2hi = (unsigned short*)(ws + 65536);             // 1MB
    unsigned short* W2lo = (unsigned short*)(ws + 65536 + 1048576);   // 1MB
    unsigned short* P1hi = (unsigned short*)(ws + 65536 + 2097152);   // 1MB
    unsigned short* P1lo = (unsigned short*)(ws + 65536 + 3145728);   // 1MB
    const size_t head = 65536 + 4194304;

    // single region: V, 16KB per row
    size_t avail = (ws_size > head) ? ws_size - head : 0;
    long maxRows = (long)(avail / ((size_t)C_DIM * E_DIM * 2));
    maxRows = (maxRows / 256) * 256;
    if (maxRows > B_DIM) maxRows = B_DIM;
    if (maxRows < 256) maxRows = 256;

    uint32_t* vbuf = (uint32_t*)(ws + head);

    k0_softmax<<<dim3(C_DIM), dim3(C_DIM), 0, stream>>>(q, whi, wlo);
    kP_split<<<dim3(512), 256, 0, stream>>>(W2, W2hi, W2lo);   // 524288 floats / 4 / 256
    kP_split<<<dim3(512), 256, 0, stream>>>(P1, P1hi, P1lo);

    for (int off = 0; off < B_DIM; off += (int)maxRows) {
        const int rows = (int)(((long)(B_DIM - off) < maxRows) ? (long)(B_DIM - off) : maxRows);
        k1_value<<<dim3(rows / 64, 16), 512, 0, stream>>>(samples, W1, b1, W2hi, W2lo, b2, vbuf, off);
        k23_fused<<<dim3(rows / 32), 512, 0, stream>>>(whi, wlo, vbuf, P1hi, P1lo, pb1, P2, pb2, out, off);
    }
}